// Round 1
// baseline (1554.427 us; speedup 1.0000x reference)
//
#include <hip/hip_runtime.h>

#define FDIM 64

// ---------------- CSR build ----------------

__global__ void hist_kernel(const int* __restrict__ dst, int* __restrict__ counts, int E) {
    int e = blockIdx.x * blockDim.x + threadIdx.x;
    if (e < E) atomicAdd(&counts[dst[e]], 1);
}

// exclusive scan; each block covers 1024 elements (256 thr x 4); blockSums[b] = block total
__global__ void scan_block_kernel(const int* __restrict__ in, int* __restrict__ out,
                                  int* __restrict__ blockSums, int n) {
    __shared__ int sdata[256];
    int t = threadIdx.x;
    int base = blockIdx.x * 1024 + t * 4;
    int v0 = (base + 0 < n) ? in[base + 0] : 0;
    int v1 = (base + 1 < n) ? in[base + 1] : 0;
    int v2 = (base + 2 < n) ? in[base + 2] : 0;
    int v3 = (base + 3 < n) ? in[base + 3] : 0;
    int tsum = v0 + v1 + v2 + v3;
    sdata[t] = tsum;
    __syncthreads();
    for (int off = 1; off < 256; off <<= 1) {
        int x = (t >= off) ? sdata[t - off] : 0;
        __syncthreads();
        sdata[t] += x;
        __syncthreads();
    }
    if (t == 255) blockSums[blockIdx.x] = sdata[255];
    int run = sdata[t] - tsum;  // exclusive prefix for this thread
    if (base + 0 < n) out[base + 0] = run; run += v0;
    if (base + 1 < n) out[base + 1] = run; run += v1;
    if (base + 2 < n) out[base + 2] = run; run += v2;
    if (base + 3 < n) out[base + 3] = run;
}

__global__ void add_off_kernel(int* __restrict__ row_start, const int* __restrict__ blockSums,
                               int* __restrict__ cursor, int n) {
    int i = blockIdx.x * blockDim.x + threadIdx.x;
    if (i < n) {
        int v = row_start[i] + blockSums[i >> 10];
        row_start[i] = v;
        cursor[i] = v;
    }
}

__global__ void scatter_kernel(const int* __restrict__ src, const int* __restrict__ dst,
                               const float* __restrict__ w, int* __restrict__ cursor,
                               int* __restrict__ col, float* __restrict__ val, int E) {
    int e = blockIdx.x * blockDim.x + threadIdx.x;
    if (e < E) {
        int d = dst[e];
        int p = atomicAdd(&cursor[d], 1);
        col[p] = src[e];
        val[p] = -w[e];   // norm = 2*w/(-lambda_max) = -w  (lambda_max = 2)
    }
}

// ---------------- Chebyshev passes ----------------
// Wave per node, lane = feature. prop(z)[n] = sum_e val[e]*z[col[e]] - z[n]

__global__ __launch_bounds__(256) void pass1_kernel(
        const float* __restrict__ x, const int* __restrict__ row_start,
        const int* __restrict__ counts, const int* __restrict__ col,
        const float* __restrict__ val, const float* __restrict__ W,
        const float* __restrict__ bias, float* __restrict__ T1,
        float* __restrict__ out, int N) {
    __shared__ float w01[2 * FDIM * FDIM];          // W0, W1
    __shared__ __align__(16) float rows[4][2][FDIM];
    for (int i = threadIdx.x; i < 2 * FDIM * FDIM; i += 256) w01[i] = W[i];

    int wid = threadIdx.x >> 6;
    int lane = threadIdx.x & 63;
    int node = blockIdx.x * 4 + wid;
    bool active = node < N;

    float xv = 0.f, acc = 0.f;
    if (active) {
        xv = x[(size_t)node * FDIM + lane];
        acc = -xv;                                   // self loop (norm = -1)
        int s = row_start[node];
        int end = s + counts[node];
        int e = s;
        for (; e + 4 <= end; e += 4) {
            int c0 = col[e], c1 = col[e+1], c2 = col[e+2], c3 = col[e+3];
            float v0 = val[e], v1 = val[e+1], v2 = val[e+2], v3 = val[e+3];
            float t0 = x[(size_t)c0 * FDIM + lane];
            float t1 = x[(size_t)c1 * FDIM + lane];
            float t2 = x[(size_t)c2 * FDIM + lane];
            float t3 = x[(size_t)c3 * FDIM + lane];
            acc += v0 * t0 + v1 * t1 + v2 * t2 + v3 * t3;
        }
        for (; e < end; ++e) acc += val[e] * x[(size_t)col[e] * FDIM + lane];
        T1[(size_t)node * FDIM + lane] = acc;
    }
    rows[wid][0][lane] = xv;
    rows[wid][1][lane] = acc;
    __syncthreads();

    float o = 0.f;
    #pragma unroll
    for (int i = 0; i < FDIM; i += 4) {
        float4 r0 = *(const float4*)&rows[wid][0][i];
        float4 r1 = *(const float4*)&rows[wid][1][i];
        o += r0.x * w01[(i+0)*FDIM + lane] + r1.x * w01[FDIM*FDIM + (i+0)*FDIM + lane];
        o += r0.y * w01[(i+1)*FDIM + lane] + r1.y * w01[FDIM*FDIM + (i+1)*FDIM + lane];
        o += r0.z * w01[(i+2)*FDIM + lane] + r1.z * w01[FDIM*FDIM + (i+2)*FDIM + lane];
        o += r0.w * w01[(i+3)*FDIM + lane] + r1.w * w01[FDIM*FDIM + (i+3)*FDIM + lane];
    }
    if (active) out[(size_t)node * FDIM + lane] = o + bias[lane];
}

// Tnext may alias Tprev (in-place) -- no __restrict__ on those.
__global__ __launch_bounds__(256) void passk_kernel(
        const float* __restrict__ Tcur, const float* Tprev, float* Tnext,
        const int* __restrict__ row_start, const int* __restrict__ counts,
        const int* __restrict__ col, const float* __restrict__ val,
        const float* __restrict__ Wk, float* __restrict__ out, int N) {
    __shared__ float wk[FDIM * FDIM];
    __shared__ __align__(16) float rows[4][FDIM];
    for (int i = threadIdx.x; i < FDIM * FDIM; i += 256) wk[i] = Wk[i];

    int wid = threadIdx.x >> 6;
    int lane = threadIdx.x & 63;
    int node = blockIdx.x * 4 + wid;
    bool active = node < N;

    float tn = 0.f;
    if (active) {
        float acc = -Tcur[(size_t)node * FDIM + lane];  // self loop
        int s = row_start[node];
        int end = s + counts[node];
        int e = s;
        for (; e + 4 <= end; e += 4) {
            int c0 = col[e], c1 = col[e+1], c2 = col[e+2], c3 = col[e+3];
            float v0 = val[e], v1 = val[e+1], v2 = val[e+2], v3 = val[e+3];
            float t0 = Tcur[(size_t)c0 * FDIM + lane];
            float t1 = Tcur[(size_t)c1 * FDIM + lane];
            float t2 = Tcur[(size_t)c2 * FDIM + lane];
            float t3 = Tcur[(size_t)c3 * FDIM + lane];
            acc += v0 * t0 + v1 * t1 + v2 * t2 + v3 * t3;
        }
        for (; e < end; ++e) acc += val[e] * Tcur[(size_t)col[e] * FDIM + lane];
        tn = 2.f * acc - Tprev[(size_t)node * FDIM + lane];
        Tnext[(size_t)node * FDIM + lane] = tn;
    }
    rows[wid][lane] = tn;
    __syncthreads();

    float o = 0.f;
    #pragma unroll
    for (int i = 0; i < FDIM; i += 4) {
        float4 r = *(const float4*)&rows[wid][i];
        o += r.x * wk[(i+0)*FDIM + lane];
        o += r.y * wk[(i+1)*FDIM + lane];
        o += r.z * wk[(i+2)*FDIM + lane];
        o += r.w * wk[(i+3)*FDIM + lane];
    }
    if (active) out[(size_t)node * FDIM + lane] += o;
}

// ---------------- host ----------------

extern "C" void kernel_launch(void* const* d_in, const int* in_sizes, int n_in,
                              void* d_out, int out_size, void* d_ws, size_t ws_size,
                              hipStream_t stream) {
    const float* x      = (const float*)d_in[0];
    const int*   idx    = (const int*)d_in[1];
    const float* w      = (const float*)d_in[2];
    const float* weight = (const float*)d_in[3];
    const float* bias   = (const float*)d_in[4];
    float* out = (float*)d_out;

    const int N = in_sizes[0] / FDIM;
    const int E = in_sizes[2];
    const int K = in_sizes[3] / (FDIM * FDIM);

    const int* src = idx;
    const int* dst = idx + E;

    int* counts    = (int*)d_ws;
    int* row_start = counts + N;
    int* cursor    = row_start + N;
    int* blockSums = cursor + N;        // 512 slots
    int* col       = blockSums + 512;
    float* val     = (float*)(col + E);
    float* TA      = val + E;
    float* TB      = TA + (size_t)N * FDIM;

    hipMemsetAsync(counts, 0, (size_t)N * sizeof(int), stream);

    int eb = (E + 255) / 256;
    hist_kernel<<<eb, 256, 0, stream>>>(dst, counts, E);

    int nb = (N + 1023) / 1024;
    scan_block_kernel<<<nb, 256, 0, stream>>>(counts, row_start, blockSums, N);
    scan_block_kernel<<<1, 256, 0, stream>>>(blockSums, blockSums, blockSums + 500, nb);
    add_off_kernel<<<(N + 255) / 256, 256, 0, stream>>>(row_start, blockSums, cursor, N);
    scatter_kernel<<<eb, 256, 0, stream>>>(src, dst, w, cursor, col, val, E);

    int pb = (N + 3) / 4;
    pass1_kernel<<<pb, 256, 0, stream>>>(x, row_start, counts, col, val, weight, bias,
                                         TA, out, N);

    const float* Tprev = x;
    float* Tcur = TA;
    float* Tnext = TB;
    for (int k = 2; k < K; ++k) {
        passk_kernel<<<pb, 256, 0, stream>>>(Tcur, Tprev, Tnext, row_start, counts,
                                             col, val, weight + (size_t)k * FDIM * FDIM,
                                             out, N);
        const float* nTprev = Tcur;
        float* nTcur = Tnext;
        float* nTnext = Tcur;   // in-place: overwrite the buffer holding new Tprev
        Tprev = nTprev; Tcur = nTcur; Tnext = nTnext;
    }
}

// Round 2
// 1520.305 us; speedup vs baseline: 1.0224x; 1.0224x over previous
//
#include <hip/hip_runtime.h>
#include <hip/hip_fp16.h>

#define FDIM 64

// ---------------- CSR build ----------------

__global__ void hist_kernel(const int* __restrict__ dst, int* __restrict__ counts, int E) {
    int e = blockIdx.x * blockDim.x + threadIdx.x;
    if (e < E) atomicAdd(&counts[dst[e]], 1);
}

// exclusive scan; each block covers 1024 elements (256 thr x 4); blockSums[b] = block total
__global__ void scan_block_kernel(const int* __restrict__ in, int* __restrict__ out,
                                  int* __restrict__ blockSums, int n) {
    __shared__ int sdata[256];
    int t = threadIdx.x;
    int base = blockIdx.x * 1024 + t * 4;
    int v0 = (base + 0 < n) ? in[base + 0] : 0;
    int v1 = (base + 1 < n) ? in[base + 1] : 0;
    int v2 = (base + 2 < n) ? in[base + 2] : 0;
    int v3 = (base + 3 < n) ? in[base + 3] : 0;
    int tsum = v0 + v1 + v2 + v3;
    sdata[t] = tsum;
    __syncthreads();
    for (int off = 1; off < 256; off <<= 1) {
        int x = (t >= off) ? sdata[t - off] : 0;
        __syncthreads();
        sdata[t] += x;
        __syncthreads();
    }
    if (t == 255) blockSums[blockIdx.x] = sdata[255];
    int run = sdata[t] - tsum;  // exclusive prefix for this thread
    if (base + 0 < n) out[base + 0] = run; run += v0;
    if (base + 1 < n) out[base + 1] = run; run += v1;
    if (base + 2 < n) out[base + 2] = run; run += v2;
    if (base + 3 < n) out[base + 3] = run;
}

__global__ void add_off_kernel(int* __restrict__ row_start, const int* __restrict__ blockSums,
                               int* __restrict__ cursor, int n) {
    int i = blockIdx.x * blockDim.x + threadIdx.x;
    if (i < n) {
        int v = row_start[i] + blockSums[i >> 10];
        row_start[i] = v;
        cursor[i] = v;
    }
}

__global__ void scatter_kernel(const int* __restrict__ src, const int* __restrict__ dst,
                               const float* __restrict__ w, int* __restrict__ cursor,
                               int* __restrict__ col, float* __restrict__ val, int E) {
    int e = blockIdx.x * blockDim.x + threadIdx.x;
    if (e < E) {
        int d = dst[e];
        int p = atomicAdd(&cursor[d], 1);
        col[p] = src[e];
        val[p] = -w[e];   // norm = 2*w/(-lambda_max) = -w  (lambda_max = 2)
    }
}

// ---------------- convert x -> fp16, and out = x@W0 + bias ----------------

__global__ __launch_bounds__(256, 8) void convert_gemm0_kernel(
        const float* __restrict__ x, const float* __restrict__ W0,
        const float* __restrict__ bias, __half* __restrict__ XH,
        float* __restrict__ out, int N) {
    __shared__ float wk[FDIM * FDIM];
    __shared__ __align__(16) float rows[4][FDIM];
    for (int i = threadIdx.x; i < FDIM * FDIM; i += 256) wk[i] = W0[i];

    int wid = threadIdx.x >> 6;
    int lane = threadIdx.x & 63;
    int node = blockIdx.x * 4 + wid;
    bool active = node < N;

    float xv = 0.f;
    if (active) {
        xv = x[(size_t)node * FDIM + lane];
        XH[(size_t)node * FDIM + lane] = __float2half(xv);
    }
    rows[wid][lane] = xv;
    __syncthreads();

    float o = 0.f;
    #pragma unroll
    for (int i = 0; i < FDIM; i += 4) {
        float4 r = *(const float4*)&rows[wid][i];
        o += r.x * wk[(i+0)*FDIM + lane];
        o += r.y * wk[(i+1)*FDIM + lane];
        o += r.z * wk[(i+2)*FDIM + lane];
        o += r.w * wk[(i+3)*FDIM + lane];
    }
    if (active) out[(size_t)node * FDIM + lane] = o + bias[lane];
}

// ---------------- Chebyshev passes ----------------
// Wave per node, lane = feature. Stored T's are fp16, scaled by sigma_k = 4^k.
// prop'(z')[n] = sum_e val[e]*z'[col[e]] - z'[n]   (in stored units)

__global__ __launch_bounds__(256, 8) void pass1_kernel(
        const __half* __restrict__ XH, const int* __restrict__ row_start,
        const int* __restrict__ counts, const int* __restrict__ col,
        const float* __restrict__ val, const float* __restrict__ W1,
        __half* __restrict__ T1H, float* __restrict__ out, int N) {
    __shared__ float wk[FDIM * FDIM];
    __shared__ __align__(16) float rows[4][FDIM];
    for (int i = threadIdx.x; i < FDIM * FDIM; i += 256) wk[i] = W1[i];

    int wid = threadIdx.x >> 6;
    int lane = threadIdx.x & 63;
    int node = blockIdx.x * 4 + wid;
    bool active = node < N;

    float acc = 0.f;
    if (active) {
        acc = -__half2float(XH[(size_t)node * FDIM + lane]);   // self loop (norm -1)
        int s = row_start[node];
        int end = s + counts[node];
        int e = s;
        for (; e + 4 <= end; e += 4) {
            int c0 = col[e], c1 = col[e+1], c2 = col[e+2], c3 = col[e+3];
            float v0 = val[e], v1 = val[e+1], v2 = val[e+2], v3 = val[e+3];
            float t0 = __half2float(XH[(size_t)c0 * FDIM + lane]);
            float t1 = __half2float(XH[(size_t)c1 * FDIM + lane]);
            float t2 = __half2float(XH[(size_t)c2 * FDIM + lane]);
            float t3 = __half2float(XH[(size_t)c3 * FDIM + lane]);
            acc += v0 * t0 + v1 * t1 + v2 * t2 + v3 * t3;
        }
        for (; e < end; ++e)
            acc += val[e] * __half2float(XH[(size_t)col[e] * FDIM + lane]);
        // T1 = acc (true units, sigma1 = 4): store scaled
        T1H[(size_t)node * FDIM + lane] = __float2half(acc * 0.25f);
    }
    rows[wid][lane] = acc;   // true T1 value for GEMM
    __syncthreads();

    float o = 0.f;
    #pragma unroll
    for (int i = 0; i < FDIM; i += 4) {
        float4 r = *(const float4*)&rows[wid][i];
        o += r.x * wk[(i+0)*FDIM + lane];
        o += r.y * wk[(i+1)*FDIM + lane];
        o += r.z * wk[(i+2)*FDIM + lane];
        o += r.w * wk[(i+3)*FDIM + lane];
    }
    if (active) out[(size_t)node * FDIM + lane] += o;
}

// sigma_cur = 4^{k-1}, sigma_prev = 4^{k-2}, sigma_next = 4^k.
// T'_next = 0.5*prop'(T'_cur) - T'_prev/16 ; true T_next = sig_n * T'_next
__global__ __launch_bounds__(256, 8) void passk_kernel(
        const __half* __restrict__ TcH, const __half* __restrict__ TpH,
        __half* __restrict__ TnH, const int* __restrict__ row_start,
        const int* __restrict__ counts, const int* __restrict__ col,
        const float* __restrict__ val, const float* __restrict__ Wk,
        float* __restrict__ out, float sig_n, int N) {
    __shared__ float wk[FDIM * FDIM];
    __shared__ __align__(16) float rows[4][FDIM];
    for (int i = threadIdx.x; i < FDIM * FDIM; i += 256) wk[i] = Wk[i];

    int wid = threadIdx.x >> 6;
    int lane = threadIdx.x & 63;
    int node = blockIdx.x * 4 + wid;
    bool active = node < N;

    float tn_true = 0.f;
    if (active) {
        size_t self = (size_t)node * FDIM + lane;
        float acc = -__half2float(TcH[self]);                  // self loop
        int s = row_start[node];
        int end = s + counts[node];
        int e = s;
        for (; e + 4 <= end; e += 4) {
            int c0 = col[e], c1 = col[e+1], c2 = col[e+2], c3 = col[e+3];
            float v0 = val[e], v1 = val[e+1], v2 = val[e+2], v3 = val[e+3];
            float t0 = __half2float(TcH[(size_t)c0 * FDIM + lane]);
            float t1 = __half2float(TcH[(size_t)c1 * FDIM + lane]);
            float t2 = __half2float(TcH[(size_t)c2 * FDIM + lane]);
            float t3 = __half2float(TcH[(size_t)c3 * FDIM + lane]);
            acc += v0 * t0 + v1 * t1 + v2 * t2 + v3 * t3;
        }
        for (; e < end; ++e)
            acc += val[e] * __half2float(TcH[(size_t)col[e] * FDIM + lane]);
        float tn_scaled = 0.5f * acc - 0.0625f * __half2float(TpH[self]);
        TnH[self] = __float2half(tn_scaled);
        tn_true = sig_n * tn_scaled;
    }
    rows[wid][lane] = tn_true;
    __syncthreads();

    float o = 0.f;
    #pragma unroll
    for (int i = 0; i < FDIM; i += 4) {
        float4 r = *(const float4*)&rows[wid][i];
        o += r.x * wk[(i+0)*FDIM + lane];
        o += r.y * wk[(i+1)*FDIM + lane];
        o += r.z * wk[(i+2)*FDIM + lane];
        o += r.w * wk[(i+3)*FDIM + lane];
    }
    if (active) out[(size_t)node * FDIM + lane] += o;
}

// ---------------- host ----------------

extern "C" void kernel_launch(void* const* d_in, const int* in_sizes, int n_in,
                              void* d_out, int out_size, void* d_ws, size_t ws_size,
                              hipStream_t stream) {
    const float* x      = (const float*)d_in[0];
    const int*   idx    = (const int*)d_in[1];
    const float* w      = (const float*)d_in[2];
    const float* weight = (const float*)d_in[3];
    const float* bias   = (const float*)d_in[4];
    float* out = (float*)d_out;

    const int N = in_sizes[0] / FDIM;
    const int E = in_sizes[2];
    const int K = in_sizes[3] / (FDIM * FDIM);

    const int* src = idx;
    const int* dst = idx + E;

    int* counts    = (int*)d_ws;
    int* row_start = counts + N;
    int* cursor    = row_start + N;
    int* blockSums = cursor + N;        // 512 slots
    int* col       = blockSums + 512;
    float* val     = (float*)(col + E);
    __half* B0     = (__half*)(val + E);            // XH = T0'
    __half* B1     = B0 + (size_t)N * FDIM;         // T1'
    __half* B2     = B1 + (size_t)N * FDIM;

    hipMemsetAsync(counts, 0, (size_t)N * sizeof(int), stream);

    int eb = (E + 255) / 256;
    hist_kernel<<<eb, 256, 0, stream>>>(dst, counts, E);

    int nb = (N + 1023) / 1024;
    scan_block_kernel<<<nb, 256, 0, stream>>>(counts, row_start, blockSums, N);
    scan_block_kernel<<<1, 256, 0, stream>>>(blockSums, blockSums, blockSums + 500, nb);
    add_off_kernel<<<(N + 255) / 256, 256, 0, stream>>>(row_start, blockSums, cursor, N);
    scatter_kernel<<<eb, 256, 0, stream>>>(src, dst, w, cursor, col, val, E);

    int pb = (N + 3) / 4;
    convert_gemm0_kernel<<<pb, 256, 0, stream>>>(x, weight, bias, B0, out, N);

    pass1_kernel<<<pb, 256, 0, stream>>>(B0, row_start, counts, col, val,
                                         weight + (size_t)FDIM * FDIM, B1, out, N);

    // 3-buffer rotation: at step k write over the buffer holding T_{k-3}
    __half* cur = B1;    // T1'
    __half* prev = B0;   // T0'
    __half* nxt = B2;
    float sig_n = 16.f;  // 4^2
    for (int k = 2; k < K; ++k) {
        passk_kernel<<<pb, 256, 0, stream>>>(cur, prev, nxt, row_start, counts,
                                             col, val, weight + (size_t)k * FDIM * FDIM,
                                             out, sig_n, N);
        __half* t = prev;
        prev = cur;
        cur = nxt;
        nxt = t;
        sig_n *= 4.f;
    }
}

// Round 3
// 1346.539 us; speedup vs baseline: 1.1544x; 1.1290x over previous
//
#include <hip/hip_runtime.h>
#include <hip/hip_fp16.h>

#define FDIM 64

// ---------------- CSR build ----------------

__global__ void hist_kernel(const int* __restrict__ dst, int* __restrict__ counts, int E) {
    int e = blockIdx.x * blockDim.x + threadIdx.x;
    if (e < E) atomicAdd(&counts[dst[e]], 1);
}

// exclusive scan; each block covers 1024 elements (256 thr x 4); blockSums[b] = block total
__global__ void scan_block_kernel(const int* __restrict__ in, int* __restrict__ out,
                                  int* __restrict__ blockSums, int n) {
    __shared__ int sdata[256];
    int t = threadIdx.x;
    int base = blockIdx.x * 1024 + t * 4;
    int v0 = (base + 0 < n) ? in[base + 0] : 0;
    int v1 = (base + 1 < n) ? in[base + 1] : 0;
    int v2 = (base + 2 < n) ? in[base + 2] : 0;
    int v3 = (base + 3 < n) ? in[base + 3] : 0;
    int tsum = v0 + v1 + v2 + v3;
    sdata[t] = tsum;
    __syncthreads();
    for (int off = 1; off < 256; off <<= 1) {
        int x = (t >= off) ? sdata[t - off] : 0;
        __syncthreads();
        sdata[t] += x;
        __syncthreads();
    }
    if (t == 255) blockSums[blockIdx.x] = sdata[255];
    int run = sdata[t] - tsum;  // exclusive prefix for this thread
    if (base + 0 < n) out[base + 0] = run; run += v0;
    if (base + 1 < n) out[base + 1] = run; run += v1;
    if (base + 2 < n) out[base + 2] = run; run += v2;
    if (base + 3 < n) out[base + 3] = run;
}

__global__ void add_off_kernel(int* __restrict__ row_start, const int* __restrict__ blockSums,
                               int* __restrict__ cursor, int n) {
    int i = blockIdx.x * blockDim.x + threadIdx.x;
    if (i < n) {
        int v = row_start[i] + blockSums[i >> 10];
        row_start[i] = v;
        cursor[i] = v;
    }
}

// packed (col, val) -> single 8B store per edge (halves random-write lines)
__global__ void scatter_kernel(const int* __restrict__ src, const int* __restrict__ dst,
                               const float* __restrict__ w, int* __restrict__ cursor,
                               int2* __restrict__ colval, int E) {
    int e = blockIdx.x * blockDim.x + threadIdx.x;
    if (e < E) {
        int d = dst[e];
        int p = atomicAdd(&cursor[d], 1);
        colval[p] = make_int2(src[e], __float_as_int(-w[e]));  // norm = -w (lambda_max=2)
    }
}

// ---------------- convert x -> fp16, and out = x@W0 + bias ----------------

__global__ __launch_bounds__(256, 8) void convert_gemm0_kernel(
        const float* __restrict__ x, const float* __restrict__ W0,
        const float* __restrict__ bias, __half* __restrict__ XH,
        float* __restrict__ out, int N) {
    __shared__ float wk[FDIM * FDIM];
    __shared__ __align__(16) float rows[4][FDIM];
    {
        const float4* Wv = (const float4*)W0;
        float4* wv = (float4*)wk;
        for (int i = threadIdx.x; i < FDIM * FDIM / 4; i += 256) wv[i] = Wv[i];
    }

    int wid = threadIdx.x >> 6;
    int lane = threadIdx.x & 63;
    int node = blockIdx.x * 4 + wid;
    bool active = node < N;

    float xv = 0.f;
    if (active) {
        xv = x[(size_t)node * FDIM + lane];
        XH[(size_t)node * FDIM + lane] = __float2half(xv);
    }
    rows[wid][lane] = xv;
    __syncthreads();

    float o = 0.f;
    #pragma unroll
    for (int i = 0; i < FDIM; i += 4) {
        float4 r = *(const float4*)&rows[wid][i];
        o += r.x * wk[(i+0)*FDIM + lane];
        o += r.y * wk[(i+1)*FDIM + lane];
        o += r.z * wk[(i+2)*FDIM + lane];
        o += r.w * wk[(i+3)*FDIM + lane];
    }
    if (active) out[(size_t)node * FDIM + lane] = o + bias[lane];
}

// ---------------- Chebyshev passes ----------------
// Wave per node, lane = feature. Stored T's are fp16, scaled by sigma_k = 4^k.
// Edge list (<=64 edges) loaded with ONE per-lane int2 load, broadcast via __shfl.

#define GATHER_LOOP(SRC, ACC)                                                       \
    {                                                                               \
        int m = (cnt < 64) ? cnt : 64;                                              \
        int2 my = (lane < m) ? cv[lane] : make_int2(0, 0);                          \
        int cx = my.x;                                                              \
        float vv = __int_as_float(my.y);                                            \
        int j = 0;                                                                  \
        for (; j + 8 <= m; j += 8) {                                                \
            int c0 = __shfl(cx, j+0); float v0 = __shfl(vv, j+0);                   \
            int c1 = __shfl(cx, j+1); float v1 = __shfl(vv, j+1);                   \
            int c2 = __shfl(cx, j+2); float v2 = __shfl(vv, j+2);                   \
            int c3 = __shfl(cx, j+3); float v3 = __shfl(vv, j+3);                   \
            int c4 = __shfl(cx, j+4); float v4 = __shfl(vv, j+4);                   \
            int c5 = __shfl(cx, j+5); float v5 = __shfl(vv, j+5);                   \
            int c6 = __shfl(cx, j+6); float v6 = __shfl(vv, j+6);                   \
            int c7 = __shfl(cx, j+7); float v7 = __shfl(vv, j+7);                   \
            float t0 = __half2float(SRC[(size_t)c0 * FDIM + lane]);                 \
            float t1 = __half2float(SRC[(size_t)c1 * FDIM + lane]);                 \
            float t2 = __half2float(SRC[(size_t)c2 * FDIM + lane]);                 \
            float t3 = __half2float(SRC[(size_t)c3 * FDIM + lane]);                 \
            float t4 = __half2float(SRC[(size_t)c4 * FDIM + lane]);                 \
            float t5 = __half2float(SRC[(size_t)c5 * FDIM + lane]);                 \
            float t6 = __half2float(SRC[(size_t)c6 * FDIM + lane]);                 \
            float t7 = __half2float(SRC[(size_t)c7 * FDIM + lane]);                 \
            ACC += v0*t0 + v1*t1 + v2*t2 + v3*t3 + v4*t4 + v5*t5 + v6*t6 + v7*t7;   \
        }                                                                           \
        for (; j < m; ++j) {                                                        \
            int c = __shfl(cx, j); float v = __shfl(vv, j);                         \
            ACC += v * __half2float(SRC[(size_t)c * FDIM + lane]);                  \
        }                                                                           \
        for (int e2 = 64; e2 < cnt; ++e2) {  /* astronomically rare */              \
            int2 a = cv[e2];                                                        \
            ACC += __int_as_float(a.y) * __half2float(SRC[(size_t)a.x * FDIM + lane]); \
        }                                                                           \
    }

__global__ __launch_bounds__(256, 8) void pass1_kernel(
        const __half* __restrict__ XH, const int* __restrict__ row_start,
        const int* __restrict__ counts, const int2* __restrict__ colval,
        const float* __restrict__ W1, __half* __restrict__ T1H,
        float* __restrict__ out, int N) {
    __shared__ float wk[FDIM * FDIM];
    __shared__ __align__(16) float rows[4][FDIM];
    {
        const float4* Wv = (const float4*)W1;
        float4* wv = (float4*)wk;
        for (int i = threadIdx.x; i < FDIM * FDIM / 4; i += 256) wv[i] = Wv[i];
    }

    int wid = threadIdx.x >> 6;
    int lane = threadIdx.x & 63;
    int node = blockIdx.x * 4 + wid;
    bool active = node < N;

    float acc = 0.f;
    if (active) {
        acc = -__half2float(XH[(size_t)node * FDIM + lane]);   // self loop (norm -1)
        int s = row_start[node];
        int cnt = counts[node];
        const int2* cv = colval + s;
        GATHER_LOOP(XH, acc)
        // T1 = acc (true units); sigma1 = 4: store scaled
        T1H[(size_t)node * FDIM + lane] = __float2half(acc * 0.25f);
    }
    rows[wid][lane] = acc;   // true T1 value for GEMM
    __syncthreads();

    float o = 0.f;
    #pragma unroll
    for (int i = 0; i < FDIM; i += 4) {
        float4 r = *(const float4*)&rows[wid][i];
        o += r.x * wk[(i+0)*FDIM + lane];
        o += r.y * wk[(i+1)*FDIM + lane];
        o += r.z * wk[(i+2)*FDIM + lane];
        o += r.w * wk[(i+3)*FDIM + lane];
    }
    if (active) out[(size_t)node * FDIM + lane] += o;
}

// sigma_cur = 4^{k-1}, sigma_prev = 4^{k-2}, sigma_next = 4^k.
// T'_next = 0.5*prop'(T'_cur) - T'_prev/16 ; true T_next = sig_n * T'_next
__global__ __launch_bounds__(256, 8) void passk_kernel(
        const __half* __restrict__ TcH, const __half* __restrict__ TpH,
        __half* __restrict__ TnH, const int* __restrict__ row_start,
        const int* __restrict__ counts, const int2* __restrict__ colval,
        const float* __restrict__ Wk, float* __restrict__ out,
        float sig_n, int N) {
    __shared__ float wk[FDIM * FDIM];
    __shared__ __align__(16) float rows[4][FDIM];
    {
        const float4* Wv = (const float4*)Wk;
        float4* wv = (float4*)wk;
        for (int i = threadIdx.x; i < FDIM * FDIM / 4; i += 256) wv[i] = Wv[i];
    }

    int wid = threadIdx.x >> 6;
    int lane = threadIdx.x & 63;
    int node = blockIdx.x * 4 + wid;
    bool active = node < N;

    float tn_true = 0.f;
    if (active) {
        size_t self = (size_t)node * FDIM + lane;
        int s = row_start[node];
        int cnt = counts[node];
        const int2* cv = colval + s;
        float acc = -__half2float(TcH[self]);                  // self loop
        GATHER_LOOP(TcH, acc)
        float tns = 0.5f * acc - 0.0625f * __half2float(TpH[self]);
        TnH[self] = __float2half(tns);
        tn_true = sig_n * tns;
    }
    rows[wid][lane] = tn_true;
    __syncthreads();

    float o = 0.f;
    #pragma unroll
    for (int i = 0; i < FDIM; i += 4) {
        float4 r = *(const float4*)&rows[wid][i];
        o += r.x * wk[(i+0)*FDIM + lane];
        o += r.y * wk[(i+1)*FDIM + lane];
        o += r.z * wk[(i+2)*FDIM + lane];
        o += r.w * wk[(i+3)*FDIM + lane];
    }
    if (active) out[(size_t)node * FDIM + lane] += o;
}

// ---------------- host ----------------

extern "C" void kernel_launch(void* const* d_in, const int* in_sizes, int n_in,
                              void* d_out, int out_size, void* d_ws, size_t ws_size,
                              hipStream_t stream) {
    const float* x      = (const float*)d_in[0];
    const int*   idx    = (const int*)d_in[1];
    const float* w      = (const float*)d_in[2];
    const float* weight = (const float*)d_in[3];
    const float* bias   = (const float*)d_in[4];
    float* out = (float*)d_out;

    const int N = in_sizes[0] / FDIM;
    const int E = in_sizes[2];
    const int K = in_sizes[3] / (FDIM * FDIM);

    const int* src = idx;
    const int* dst = idx + E;

    int* counts    = (int*)d_ws;
    int* row_start = counts + N;
    int* cursor    = row_start + N;
    int* blockSums = cursor + N;        // 512 slots
    int2* colval   = (int2*)(blockSums + 512);      // 3N+512 ints -> 8B aligned
    __half* B0     = (__half*)(colval + E);         // XH = T0'
    __half* B1     = B0 + (size_t)N * FDIM;         // T1'
    __half* B2     = B1 + (size_t)N * FDIM;

    hipMemsetAsync(counts, 0, (size_t)N * sizeof(int), stream);

    int eb = (E + 255) / 256;
    hist_kernel<<<eb, 256, 0, stream>>>(dst, counts, E);

    int nb = (N + 1023) / 1024;
    scan_block_kernel<<<nb, 256, 0, stream>>>(counts, row_start, blockSums, N);
    scan_block_kernel<<<1, 256, 0, stream>>>(blockSums, blockSums, blockSums + 500, nb);
    add_off_kernel<<<(N + 255) / 256, 256, 0, stream>>>(row_start, blockSums, cursor, N);
    scatter_kernel<<<eb, 256, 0, stream>>>(src, dst, w, cursor, colval, E);

    int pb = (N + 3) / 4;
    convert_gemm0_kernel<<<pb, 256, 0, stream>>>(x, weight, bias, B0, out, N);

    pass1_kernel<<<pb, 256, 0, stream>>>(B0, row_start, counts, colval,
                                         weight + (size_t)FDIM * FDIM, B1, out, N);

    // 3-buffer rotation: at step k write over the buffer holding T_{k-2}'s prev
    __half* cur = B1;    // T1'
    __half* prev = B0;   // T0'
    __half* nxt = B2;
    float sig_n = 16.f;  // 4^2
    for (int k = 2; k < K; ++k) {
        passk_kernel<<<pb, 256, 0, stream>>>(cur, prev, nxt, row_start, counts,
                                             colval, weight + (size_t)k * FDIM * FDIM,
                                             out, sig_n, N);
        __half* t = prev;
        prev = cur;
        cur = nxt;
        nxt = t;
        sig_n *= 4.f;
    }
}

// Round 5
// 1047.816 us; speedup vs baseline: 1.4835x; 1.2851x over previous
//
#include <hip/hip_runtime.h>
#include <hip/hip_fp16.h>

#define FDIM 64
#define NB_SHIFT 10                  // 1024 nodes per bucket
#define NB_PAD 256                   // padded scan width (NB <= 256)
#define CH 4096                      // edges per bin-chunk

// ---------------- CSR build ----------------

__global__ void hist_kernel(const int* __restrict__ dst, int* __restrict__ counts, int E) {
    int e = blockIdx.x * blockDim.x + threadIdx.x;
    if (e < E) atomicAdd(&counts[dst[e]], 1);
}

// exclusive scan; each block covers 1024 elements (256 thr x 4); blockSums[b] = block total
__global__ void scan_block_kernel(const int* __restrict__ in, int* __restrict__ out,
                                  int* __restrict__ blockSums, int n) {
    __shared__ int sdata[256];
    int t = threadIdx.x;
    int base = blockIdx.x * 1024 + t * 4;
    int v0 = (base + 0 < n) ? in[base + 0] : 0;
    int v1 = (base + 1 < n) ? in[base + 1] : 0;
    int v2 = (base + 2 < n) ? in[base + 2] : 0;
    int v3 = (base + 3 < n) ? in[base + 3] : 0;
    int tsum = v0 + v1 + v2 + v3;
    sdata[t] = tsum;
    __syncthreads();
    for (int off = 1; off < 256; off <<= 1) {
        int x = (t >= off) ? sdata[t - off] : 0;
        __syncthreads();
        sdata[t] += x;
        __syncthreads();
    }
    if (t == 255) blockSums[blockIdx.x] = sdata[255];
    int run = sdata[t] - tsum;  // exclusive prefix for this thread
    if (base + 0 < n) out[base + 0] = run; run += v0;
    if (base + 1 < n) out[base + 1] = run; run += v1;
    if (base + 2 < n) out[base + 2] = run; run += v2;
    if (base + 3 < n) out[base + 3] = run;
}

__global__ void add_off_kernel(int* __restrict__ row_start, const int* __restrict__ blockSums,
                               int* __restrict__ cursor, int* __restrict__ bucket_cursor,
                               int n) {
    int i = blockIdx.x * blockDim.x + threadIdx.x;
    if (i < n) {
        int v = row_start[i] + blockSums[i >> 10];
        row_start[i] = v;
        cursor[i] = v;
        if ((i & ((1 << NB_SHIFT) - 1)) == 0) bucket_cursor[i >> NB_SHIFT] = v;
    }
}

// Stage 1: bin edges by dst bucket with LDS staging + chunked coalesced flush.
__global__ __launch_bounds__(256) void bin_kernel(
        const int* __restrict__ src, const int* __restrict__ dst,
        const float* __restrict__ w, int* __restrict__ bucket_cursor,
        int2* __restrict__ binned_sv, unsigned short* __restrict__ binned_d,
        int E, int NB) {
    __shared__ int2 stage_sv[CH];           // 32 KB
    __shared__ int  stage_d[CH];            // 16 KB
    __shared__ int hist[NB_PAD], offs0[NB_PAD], run[NB_PAD], base[NB_PAD];

    int t = threadIdx.x;
    int c0 = blockIdx.x * CH;
    int valid = E - c0; if (valid > CH) valid = CH;

    for (int b = t; b < NB_PAD; b += 256) hist[b] = 0;
    __syncthreads();

    int  myd[16];
    int2 mysv[16];
    #pragma unroll
    for (int j = 0; j < 16; ++j) {
        int i = t + j * 256;
        if (i < valid) {
            int e = c0 + i;
            int d = dst[e];
            myd[j] = d;
            mysv[j] = make_int2(src[e], __float_as_int(-w[e]));  // norm = -w
            atomicAdd(&hist[d >> NB_SHIFT], 1);
        } else myd[j] = -1;
    }
    __syncthreads();

    // inclusive scan of hist (256-wide Hillis-Steele) -> exclusive offs
    offs0[t] = hist[t];
    __syncthreads();
    for (int off = 1; off < 256; off <<= 1) {
        int x = (t >= off) ? offs0[t - off] : 0;
        __syncthreads();
        offs0[t] += x;
        __syncthreads();
    }
    int cnt_b = hist[t];
    int excl = offs0[t] - cnt_b;
    __syncthreads();
    offs0[t] = excl;
    run[t] = excl;
    base[t] = (t < NB && cnt_b > 0) ? atomicAdd(&bucket_cursor[t], cnt_b) : 0;
    __syncthreads();

    // scatter into LDS grouped by bucket
    #pragma unroll
    for (int j = 0; j < 16; ++j) {
        if (myd[j] >= 0) {
            int b = myd[j] >> NB_SHIFT;
            int pos = atomicAdd(&run[b], 1);
            stage_sv[pos] = mysv[j];
            stage_d[pos]  = myd[j];
        }
    }
    __syncthreads();

    // flush: consecutive LDS entries of a bucket -> consecutive global slots
    for (int i = t; i < valid; i += 256) {
        int d = stage_d[i];
        int b = d >> NB_SHIFT;
        int g = base[b] + (i - offs0[b]);
        binned_sv[g] = stage_sv[i];
        binned_d[g]  = (unsigned short)(d & ((1 << NB_SHIFT) - 1));
    }
}

// Stage 2: within-bucket placement; writes land in the bucket's ~L2-resident CSR window.
__global__ __launch_bounds__(256) void csr_kernel(
        const int* __restrict__ row_start, const int2* __restrict__ binned_sv,
        const unsigned short* __restrict__ binned_d, int* __restrict__ cursor,
        int2* __restrict__ colval, int E, int N) {
    int b = blockIdx.x >> 1;
    int half = blockIdx.x & 1;
    int nbase = b << NB_SHIFT;
    int nextNode = (b + 1) << NB_SHIFT;
    int lo = row_start[nbase];
    int hi = (nextNode < N) ? row_start[nextNode] : E;
    for (int i = lo + half * 256 + threadIdx.x; i < hi; i += 512) {
        int2 sv = binned_sv[i];
        int d = nbase + binned_d[i];
        int p = atomicAdd(&cursor[d], 1);
        colval[p] = sv;
    }
}

// ---------------- convert x -> fp16 (T0') ----------------

__global__ void convert_kernel(const float* __restrict__ x, __half* __restrict__ XH,
                               int total) {
    int i = (blockIdx.x * blockDim.x + threadIdx.x) * 4;
    if (i < total) {
        float4 v = *(const float4*)(x + i);
        __half2 h0 = __floats2half2_rn(v.x, v.y);
        __half2 h1 = __floats2half2_rn(v.z, v.w);
        int2 packed = make_int2(*(int*)&h0, *(int*)&h1);
        *(int2*)((char*)XH + (size_t)i * 2) = packed;
    }
}

// ---------------- Chebyshev passes (no GEMM, no LDS) ----------------
// Wave per node, lane = feature. Stored T's are fp16, scaled by sigma_k = 4^k.

#define GATHER_LOOP(SRC, ACC)                                                       \
    {                                                                               \
        int m = (cnt < 64) ? cnt : 64;                                              \
        int2 my = (lane < m) ? cv[lane] : make_int2(0, 0);                          \
        int cx = my.x;                                                              \
        float vv = __int_as_float(my.y);                                            \
        int j = 0;                                                                  \
        for (; j + 8 <= m; j += 8) {                                                \
            int c0 = __shfl(cx, j+0); float v0 = __shfl(vv, j+0);                   \
            int c1 = __shfl(cx, j+1); float v1 = __shfl(vv, j+1);                   \
            int c2 = __shfl(cx, j+2); float v2 = __shfl(vv, j+2);                   \
            int c3 = __shfl(cx, j+3); float v3 = __shfl(vv, j+3);                   \
            int c4 = __shfl(cx, j+4); float v4 = __shfl(vv, j+4);                   \
            int c5 = __shfl(cx, j+5); float v5 = __shfl(vv, j+5);                   \
            int c6 = __shfl(cx, j+6); float v6 = __shfl(vv, j+6);                   \
            int c7 = __shfl(cx, j+7); float v7 = __shfl(vv, j+7);                   \
            float t0 = __half2float(SRC[(size_t)c0 * FDIM + lane]);                 \
            float t1 = __half2float(SRC[(size_t)c1 * FDIM + lane]);                 \
            float t2 = __half2float(SRC[(size_t)c2 * FDIM + lane]);                 \
            float t3 = __half2float(SRC[(size_t)c3 * FDIM + lane]);                 \
            float t4 = __half2float(SRC[(size_t)c4 * FDIM + lane]);                 \
            float t5 = __half2float(SRC[(size_t)c5 * FDIM + lane]);                 \
            float t6 = __half2float(SRC[(size_t)c6 * FDIM + lane]);                 \
            float t7 = __half2float(SRC[(size_t)c7 * FDIM + lane]);                 \
            ACC += v0*t0 + v1*t1 + v2*t2 + v3*t3 + v4*t4 + v5*t5 + v6*t6 + v7*t7;   \
        }                                                                           \
        for (; j < m; ++j) {                                                        \
            int c = __shfl(cx, j); float v = __shfl(vv, j);                         \
            ACC += v * __half2float(SRC[(size_t)c * FDIM + lane]);                  \
        }                                                                           \
        for (int e2 = 64; e2 < cnt; ++e2) {  /* astronomically rare */              \
            int2 a = cv[e2];                                                        \
            ACC += __int_as_float(a.y) * __half2float(SRC[(size_t)a.x * FDIM + lane]); \
        }                                                                           \
    }

__global__ __launch_bounds__(256, 8) void pass1_kernel(
        const __half* __restrict__ XH, const int* __restrict__ row_start,
        const int* __restrict__ counts, const int2* __restrict__ colval,
        __half* __restrict__ T1H, int N) {
    int wid = threadIdx.x >> 6;
    int lane = threadIdx.x & 63;
    int node = blockIdx.x * 4 + wid;
    if (node >= N) return;

    float acc = -__half2float(XH[(size_t)node * FDIM + lane]);   // self loop (norm -1)
    int s = row_start[node];
    int cnt = counts[node];
    const int2* cv = colval + s;
    GATHER_LOOP(XH, acc)
    T1H[(size_t)node * FDIM + lane] = __float2half(acc * 0.25f);  // sigma1 = 4
}

// T'_next = 0.5*prop'(T'_cur) - T'_prev/16
__global__ __launch_bounds__(256, 8) void passk_kernel(
        const __half* __restrict__ TcH, const __half* __restrict__ TpH,
        __half* __restrict__ TnH, const int* __restrict__ row_start,
        const int* __restrict__ counts, const int2* __restrict__ colval, int N) {
    int wid = threadIdx.x >> 6;
    int lane = threadIdx.x & 63;
    int node = blockIdx.x * 4 + wid;
    if (node >= N) return;

    size_t self = (size_t)node * FDIM + lane;
    int s = row_start[node];
    int cnt = counts[node];
    const int2* cv = colval + s;
    float acc = -__half2float(TcH[self]);                        // self loop
    GATHER_LOOP(TcH, acc)
    float tns = 0.5f * acc - 0.0625f * __half2float(TpH[self]);
    TnH[self] = __float2half(tns);
}

// ---------------- final: out = sum_k sigma_k * T'_k @ W_k + bias ----------------
// lane = node. Each lane reads ITS OWN node's T-row (contiguous 128B) via 16B loads;
// W is wave-uniform -> scalar broadcast loads. No LDS, no transpose.

__global__ __launch_bounds__(256) void final_kernel(
        const __half* __restrict__ Tall, const float* __restrict__ W,
        const float* __restrict__ bias, float* __restrict__ out,
        int N, int K) {
    int wid = threadIdx.x >> 6;
    int lane = threadIdx.x & 63;
    int wg = blockIdx.x * 4 + wid;
    int node = (wg << 6) + lane;
    if (node >= N) return;
    size_t NT = (size_t)N * FDIM;

    float o[FDIM];
    #pragma unroll
    for (int l = 0; l < FDIM; ++l) o[l] = bias[l];

    float sig = 1.f;
    for (int k = 0; k < K; ++k) {
        const __half* Trow = Tall + (size_t)k * NT + (size_t)node * FDIM;
        const float* Wk = W + k * FDIM * FDIM;
        for (int i8 = 0; i8 < FDIM / 8; ++i8) {
            uint4 raw = *(const uint4*)(Trow + i8 * 8);   // 8 halves, 16B
            const __half2* hp = (const __half2*)&raw;
            float tv[8];
            #pragma unroll
            for (int q = 0; q < 4; ++q) {
                float2 f = __half22float2(hp[q]);
                tv[2*q]   = sig * f.x;
                tv[2*q+1] = sig * f.y;
            }
            #pragma unroll
            for (int j = 0; j < 8; ++j) {
                const float* wrow = Wk + (i8 * 8 + j) * FDIM;
                #pragma unroll
                for (int l = 0; l < FDIM; ++l)
                    o[l] = fmaf(tv[j], wrow[l], o[l]);
            }
        }
        sig *= 4.f;
    }

    float* orow = out + (size_t)node * FDIM;
    #pragma unroll
    for (int l = 0; l < FDIM; l += 4)
        *(float4*)(orow + l) = make_float4(o[l], o[l+1], o[l+2], o[l+3]);
}

// ---------------- host ----------------

extern "C" void kernel_launch(void* const* d_in, const int* in_sizes, int n_in,
                              void* d_out, int out_size, void* d_ws, size_t ws_size,
                              hipStream_t stream) {
    const float* x      = (const float*)d_in[0];
    const int*   idx    = (const int*)d_in[1];
    const float* w      = (const float*)d_in[2];
    const float* weight = (const float*)d_in[3];
    const float* bias   = (const float*)d_in[4];
    float* out = (float*)d_out;

    const int N = in_sizes[0] / FDIM;
    const int E = in_sizes[2];
    const int K = in_sizes[3] / (FDIM * FDIM);
    const int NB = (N + (1 << NB_SHIFT) - 1) >> NB_SHIFT;

    const int* src = idx;
    const int* dst = idx + E;

    int* counts        = (int*)d_ws;                 // N
    int* row_start     = counts + N;                 // N
    int* cursor        = row_start + N;              // N
    int* blockSums     = cursor + N;                 // 512
    int* bucket_cursor = blockSums + 512;            // 256
    int2* colval       = (int2*)(bucket_cursor + 256);      // E, 8B-aligned
    __half* Tall       = (__half*)(colval + E);             // K * N*FDIM fp16
    // binned arrays alias T0/T1 (dead before convert/pass1 write them)
    int2* binned_sv    = (int2*)Tall;                       // E * 8B
    unsigned short* binned_d = (unsigned short*)(Tall + (size_t)N * FDIM);  // E * 2B

    hipMemsetAsync(counts, 0, (size_t)N * sizeof(int), stream);

    int eb = (E + 255) / 256;
    hist_kernel<<<eb, 256, 0, stream>>>(dst, counts, E);

    int nb = (N + 1023) / 1024;
    scan_block_kernel<<<nb, 256, 0, stream>>>(counts, row_start, blockSums, N);
    scan_block_kernel<<<1, 256, 0, stream>>>(blockSums, blockSums, blockSums + 500, nb);
    add_off_kernel<<<(N + 255) / 256, 256, 0, stream>>>(row_start, blockSums, cursor,
                                                        bucket_cursor, N);

    int bb = (E + CH - 1) / CH;
    bin_kernel<<<bb, 256, 0, stream>>>(src, dst, w, bucket_cursor,
                                       binned_sv, binned_d, E, NB);
    csr_kernel<<<2 * NB, 256, 0, stream>>>(row_start, binned_sv, binned_d,
                                           cursor, colval, E, N);

    // T0' = x (fp16)
    convert_kernel<<<(N * FDIM + 1023) / 1024, 256, 0, stream>>>(x, Tall, N * FDIM);

    size_t NT = (size_t)N * FDIM;
    __half* T[8];
    for (int k = 0; k < K && k < 8; ++k) T[k] = Tall + (size_t)k * NT;

    int pb = (N + 3) / 4;
    pass1_kernel<<<pb, 256, 0, stream>>>(T[0], row_start, counts, colval, T[1], N);
    for (int k = 2; k < K; ++k) {
        passk_kernel<<<pb, 256, 0, stream>>>(T[k-1], T[k-2], T[k], row_start, counts,
                                             colval, N);
    }

    int fb = (((N + 63) >> 6) + 3) / 4;
    final_kernel<<<fb, 256, 0, stream>>>(Tall, weight, bias, out, N, K);
}

// Round 6
// 896.418 us; speedup vs baseline: 1.7340x; 1.1689x over previous
//
#include <hip/hip_runtime.h>
#include <hip/hip_fp16.h>

#define FDIM 64
#define NB_SHIFT 10                  // 1024 nodes per bucket
#define NB_PAD 256                   // padded scan width (NB <= 256)
#define CH 4096                      // edges per bin-chunk

// ---------------- CSR build ----------------

__global__ void hist_kernel(const int* __restrict__ dst, int* __restrict__ counts, int E) {
    int e = blockIdx.x * blockDim.x + threadIdx.x;
    if (e < E) atomicAdd(&counts[dst[e]], 1);
}

// exclusive scan; each block covers 1024 elements (256 thr x 4); blockSums[b] = block total
__global__ void scan_block_kernel(const int* __restrict__ in, int* __restrict__ out,
                                  int* __restrict__ blockSums, int n) {
    __shared__ int sdata[256];
    int t = threadIdx.x;
    int base = blockIdx.x * 1024 + t * 4;
    int v0 = (base + 0 < n) ? in[base + 0] : 0;
    int v1 = (base + 1 < n) ? in[base + 1] : 0;
    int v2 = (base + 2 < n) ? in[base + 2] : 0;
    int v3 = (base + 3 < n) ? in[base + 3] : 0;
    int tsum = v0 + v1 + v2 + v3;
    sdata[t] = tsum;
    __syncthreads();
    for (int off = 1; off < 256; off <<= 1) {
        int x = (t >= off) ? sdata[t - off] : 0;
        __syncthreads();
        sdata[t] += x;
        __syncthreads();
    }
    if (t == 255) blockSums[blockIdx.x] = sdata[255];
    int run = sdata[t] - tsum;  // exclusive prefix for this thread
    if (base + 0 < n) out[base + 0] = run; run += v0;
    if (base + 1 < n) out[base + 1] = run; run += v1;
    if (base + 2 < n) out[base + 2] = run; run += v2;
    if (base + 3 < n) out[base + 3] = run;
}

__global__ void add_off_kernel(int* __restrict__ row_start, const int* __restrict__ blockSums,
                               int* __restrict__ bucket_cursor, int n) {
    int i = blockIdx.x * blockDim.x + threadIdx.x;
    if (i < n) {
        int v = row_start[i] + blockSums[i >> 10];
        row_start[i] = v;
        if ((i & ((1 << NB_SHIFT) - 1)) == 0) bucket_cursor[i >> NB_SHIFT] = v;
    }
}

// Stage 1: bin edges by dst bucket with LDS staging + chunked coalesced flush.
__global__ __launch_bounds__(256) void bin_kernel(
        const int* __restrict__ src, const int* __restrict__ dst,
        const float* __restrict__ w, int* __restrict__ bucket_cursor,
        int2* __restrict__ binned_sv, unsigned short* __restrict__ binned_d,
        int E, int NB) {
    __shared__ int2 stage_sv[CH];           // 32 KB
    __shared__ int  stage_d[CH];            // 16 KB
    __shared__ int hist[NB_PAD], offs0[NB_PAD], run[NB_PAD], base[NB_PAD];

    int t = threadIdx.x;
    int c0 = blockIdx.x * CH;
    int valid = E - c0; if (valid > CH) valid = CH;

    for (int b = t; b < NB_PAD; b += 256) hist[b] = 0;
    __syncthreads();

    int  myd[16];
    int2 mysv[16];
    #pragma unroll
    for (int j = 0; j < 16; ++j) {
        int i = t + j * 256;
        if (i < valid) {
            int e = c0 + i;
            int d = dst[e];
            myd[j] = d;
            mysv[j] = make_int2(src[e], __float_as_int(-w[e]));  // norm = -w
            atomicAdd(&hist[d >> NB_SHIFT], 1);
        } else myd[j] = -1;
    }
    __syncthreads();

    // inclusive scan of hist (256-wide Hillis-Steele) -> exclusive offs
    offs0[t] = hist[t];
    __syncthreads();
    for (int off = 1; off < 256; off <<= 1) {
        int x = (t >= off) ? offs0[t - off] : 0;
        __syncthreads();
        offs0[t] += x;
        __syncthreads();
    }
    int cnt_b = hist[t];
    int excl = offs0[t] - cnt_b;
    __syncthreads();
    offs0[t] = excl;
    run[t] = excl;
    base[t] = (t < NB && cnt_b > 0) ? atomicAdd(&bucket_cursor[t], cnt_b) : 0;
    __syncthreads();

    // scatter into LDS grouped by bucket
    #pragma unroll
    for (int j = 0; j < 16; ++j) {
        if (myd[j] >= 0) {
            int b = myd[j] >> NB_SHIFT;
            int pos = atomicAdd(&run[b], 1);
            stage_sv[pos] = mysv[j];
            stage_d[pos]  = myd[j];
        }
    }
    __syncthreads();

    // flush: consecutive LDS entries of a bucket -> consecutive global slots
    for (int i = t; i < valid; i += 256) {
        int d = stage_d[i];
        int b = d >> NB_SHIFT;
        int g = base[b] + (i - offs0[b]);
        binned_sv[g] = stage_sv[i];
        binned_d[g]  = (unsigned short)(d & ((1 << NB_SHIFT) - 1));
    }
}

// Stage 2: one 1024-thread block per bucket; ranks via LDS cursors seeded from
// row_start (no global atomics). All stores to the bucket's ~130KB CSR window
// come from ONE block -> one XCD's L2 -> lines fill before eviction.
__global__ __launch_bounds__(1024) void csr_kernel(
        const int* __restrict__ row_start, const int2* __restrict__ binned_sv,
        const unsigned short* __restrict__ binned_d,
        int2* __restrict__ colval, int E, int N) {
    __shared__ int lcur[1 << NB_SHIFT];     // 4 KB
    int b = blockIdx.x;
    int t = threadIdx.x;
    int nbase = b << NB_SHIFT;
    int nextNode = (b + 1) << NB_SHIFT;

    int nloc = N - nbase; if (nloc > (1 << NB_SHIFT)) nloc = 1 << NB_SHIFT;
    if (t < nloc) lcur[t] = row_start[nbase + t];
    __syncthreads();

    int lo = row_start[nbase];
    int hi = (nextNode < N) ? row_start[nextNode] : E;
    for (int i = lo + t; i < hi; i += 1024) {
        int2 sv = binned_sv[i];
        int ld = binned_d[i];
        int p = atomicAdd(&lcur[ld], 1);
        colval[p] = sv;
    }
}

// ---------------- convert x -> fp16 (T0') ----------------

__global__ void convert_kernel(const float* __restrict__ x, __half* __restrict__ XH,
                               int total) {
    int i = (blockIdx.x * blockDim.x + threadIdx.x) * 4;
    if (i < total) {
        float4 v = *(const float4*)(x + i);
        __half2 h0 = __floats2half2_rn(v.x, v.y);
        __half2 h1 = __floats2half2_rn(v.z, v.w);
        int2 packed = make_int2(*(int*)&h0, *(int*)&h1);
        *(int2*)((char*)XH + (size_t)i * 2) = packed;
    }
}

// ---------------- Chebyshev passes (no GEMM, no LDS) ----------------
// Wave per node, lane = feature. Stored T's are fp16, scaled by sigma_k = 4^k.

#define GATHER_LOOP(SRC, ACC)                                                       \
    {                                                                               \
        int m = (cnt < 64) ? cnt : 64;                                              \
        int2 my = (lane < m) ? cv[lane] : make_int2(0, 0);                          \
        int cx = my.x;                                                              \
        float vv = __int_as_float(my.y);                                            \
        int j = 0;                                                                  \
        for (; j + 8 <= m; j += 8) {                                                \
            int c0 = __shfl(cx, j+0); float v0 = __shfl(vv, j+0);                   \
            int c1 = __shfl(cx, j+1); float v1 = __shfl(vv, j+1);                   \
            int c2 = __shfl(cx, j+2); float v2 = __shfl(vv, j+2);                   \
            int c3 = __shfl(cx, j+3); float v3 = __shfl(vv, j+3);                   \
            int c4 = __shfl(cx, j+4); float v4 = __shfl(vv, j+4);                   \
            int c5 = __shfl(cx, j+5); float v5 = __shfl(vv, j+5);                   \
            int c6 = __shfl(cx, j+6); float v6 = __shfl(vv, j+6);                   \
            int c7 = __shfl(cx, j+7); float v7 = __shfl(vv, j+7);                   \
            float t0 = __half2float(SRC[(size_t)c0 * FDIM + lane]);                 \
            float t1 = __half2float(SRC[(size_t)c1 * FDIM + lane]);                 \
            float t2 = __half2float(SRC[(size_t)c2 * FDIM + lane]);                 \
            float t3 = __half2float(SRC[(size_t)c3 * FDIM + lane]);                 \
            float t4 = __half2float(SRC[(size_t)c4 * FDIM + lane]);                 \
            float t5 = __half2float(SRC[(size_t)c5 * FDIM + lane]);                 \
            float t6 = __half2float(SRC[(size_t)c6 * FDIM + lane]);                 \
            float t7 = __half2float(SRC[(size_t)c7 * FDIM + lane]);                 \
            ACC += v0*t0 + v1*t1 + v2*t2 + v3*t3 + v4*t4 + v5*t5 + v6*t6 + v7*t7;   \
        }                                                                           \
        for (; j < m; ++j) {                                                        \
            int c = __shfl(cx, j); float v = __shfl(vv, j);                         \
            ACC += v * __half2float(SRC[(size_t)c * FDIM + lane]);                  \
        }                                                                           \
        for (int e2 = 64; e2 < cnt; ++e2) {  /* astronomically rare */              \
            int2 a = cv[e2];                                                        \
            ACC += __int_as_float(a.y) * __half2float(SRC[(size_t)a.x * FDIM + lane]); \
        }                                                                           \
    }

__global__ __launch_bounds__(256, 8) void pass1_kernel(
        const __half* __restrict__ XH, const int* __restrict__ row_start,
        const int* __restrict__ counts, const int2* __restrict__ colval,
        __half* __restrict__ T1H, int N) {
    int wid = threadIdx.x >> 6;
    int lane = threadIdx.x & 63;
    int node = blockIdx.x * 4 + wid;
    if (node >= N) return;

    float acc = -__half2float(XH[(size_t)node * FDIM + lane]);   // self loop (norm -1)
    int s = row_start[node];
    int cnt = counts[node];
    const int2* cv = colval + s;
    GATHER_LOOP(XH, acc)
    T1H[(size_t)node * FDIM + lane] = __float2half(acc * 0.25f);  // sigma1 = 4
}

// T'_next = 0.5*prop'(T'_cur) - T'_prev/16
__global__ __launch_bounds__(256, 8) void passk_kernel(
        const __half* __restrict__ TcH, const __half* __restrict__ TpH,
        __half* __restrict__ TnH, const int* __restrict__ row_start,
        const int* __restrict__ counts, const int2* __restrict__ colval, int N) {
    int wid = threadIdx.x >> 6;
    int lane = threadIdx.x & 63;
    int node = blockIdx.x * 4 + wid;
    if (node >= N) return;

    size_t self = (size_t)node * FDIM + lane;
    int s = row_start[node];
    int cnt = counts[node];
    const int2* cv = colval + s;
    float acc = -__half2float(TcH[self]);                        // self loop
    GATHER_LOOP(TcH, acc)
    float tns = 0.5f * acc - 0.0625f * __half2float(TpH[self]);
    TnH[self] = __float2half(tns);
}

// ---------------- final: out = sum_k sigma_k * T'_k @ W_k + bias ----------------
// lane = node. Each lane reads ITS OWN node's T-row (contiguous 128B) via 16B loads;
// W is wave-uniform -> scalar broadcast loads. No LDS, no transpose.

__global__ __launch_bounds__(256) void final_kernel(
        const __half* __restrict__ Tall, const float* __restrict__ W,
        const float* __restrict__ bias, float* __restrict__ out,
        int N, int K) {
    int wid = threadIdx.x >> 6;
    int lane = threadIdx.x & 63;
    int wg = blockIdx.x * 4 + wid;
    int node = (wg << 6) + lane;
    if (node >= N) return;
    size_t NT = (size_t)N * FDIM;

    float o[FDIM];
    #pragma unroll
    for (int l = 0; l < FDIM; ++l) o[l] = bias[l];

    float sig = 1.f;
    for (int k = 0; k < K; ++k) {
        const __half* Trow = Tall + (size_t)k * NT + (size_t)node * FDIM;
        const float* Wk = W + k * FDIM * FDIM;
        for (int i8 = 0; i8 < FDIM / 8; ++i8) {
            uint4 raw = *(const uint4*)(Trow + i8 * 8);   // 8 halves, 16B
            const __half2* hp = (const __half2*)&raw;
            float tv[8];
            #pragma unroll
            for (int q = 0; q < 4; ++q) {
                float2 f = __half22float2(hp[q]);
                tv[2*q]   = sig * f.x;
                tv[2*q+1] = sig * f.y;
            }
            #pragma unroll
            for (int j = 0; j < 8; ++j) {
                const float* wrow = Wk + (i8 * 8 + j) * FDIM;
                #pragma unroll
                for (int l = 0; l < FDIM; ++l)
                    o[l] = fmaf(tv[j], wrow[l], o[l]);
            }
        }
        sig *= 4.f;
    }

    float* orow = out + (size_t)node * FDIM;
    #pragma unroll
    for (int l = 0; l < FDIM; l += 4)
        *(float4*)(orow + l) = make_float4(o[l], o[l+1], o[l+2], o[l+3]);
}

// ---------------- host ----------------

extern "C" void kernel_launch(void* const* d_in, const int* in_sizes, int n_in,
                              void* d_out, int out_size, void* d_ws, size_t ws_size,
                              hipStream_t stream) {
    const float* x      = (const float*)d_in[0];
    const int*   idx    = (const int*)d_in[1];
    const float* w      = (const float*)d_in[2];
    const float* weight = (const float*)d_in[3];
    const float* bias   = (const float*)d_in[4];
    float* out = (float*)d_out;

    const int N = in_sizes[0] / FDIM;
    const int E = in_sizes[2];
    const int K = in_sizes[3] / (FDIM * FDIM);
    const int NB = (N + (1 << NB_SHIFT) - 1) >> NB_SHIFT;

    const int* src = idx;
    const int* dst = idx + E;

    int* counts        = (int*)d_ws;                 // N
    int* row_start     = counts + N;                 // N
    int* blockSums     = row_start + N;              // 512
    int* bucket_cursor = blockSums + 512;            // 256
    int2* colval       = (int2*)(bucket_cursor + 256);      // E, 8B-aligned
    __half* Tall       = (__half*)(colval + E);             // K * N*FDIM fp16
    // binned arrays alias T0/T1 (dead before convert/pass1 write them)
    int2* binned_sv    = (int2*)Tall;                       // E * 8B
    unsigned short* binned_d = (unsigned short*)(Tall + (size_t)N * FDIM);  // E * 2B

    hipMemsetAsync(counts, 0, (size_t)N * sizeof(int), stream);

    int eb = (E + 255) / 256;
    hist_kernel<<<eb, 256, 0, stream>>>(dst, counts, E);

    int nb = (N + 1023) / 1024;
    scan_block_kernel<<<nb, 256, 0, stream>>>(counts, row_start, blockSums, N);
    scan_block_kernel<<<1, 256, 0, stream>>>(blockSums, blockSums, blockSums + 500, nb);
    add_off_kernel<<<(N + 255) / 256, 256, 0, stream>>>(row_start, blockSums,
                                                        bucket_cursor, N);

    int bb = (E + CH - 1) / CH;
    bin_kernel<<<bb, 256, 0, stream>>>(src, dst, w, bucket_cursor,
                                       binned_sv, binned_d, E, NB);
    csr_kernel<<<NB, 1024, 0, stream>>>(row_start, binned_sv, binned_d,
                                        colval, E, N);

    // T0' = x (fp16)
    convert_kernel<<<(N * FDIM + 1023) / 1024, 256, 0, stream>>>(x, Tall, N * FDIM);

    size_t NT = (size_t)N * FDIM;
    __half* T[8];
    for (int k = 0; k < K && k < 8; ++k) T[k] = Tall + (size_t)k * NT;

    int pb = (N + 3) / 4;
    pass1_kernel<<<pb, 256, 0, stream>>>(T[0], row_start, counts, colval, T[1], N);
    for (int k = 2; k < K; ++k) {
        passk_kernel<<<pb, 256, 0, stream>>>(T[k-1], T[k-2], T[k], row_start, counts,
                                             colval, N);
    }

    int fb = (((N + 63) >> 6) + 3) / 4;
    final_kernel<<<fb, 256, 0, stream>>>(Tall, weight, bias, out, N, K);
}

// Round 7
// 841.627 us; speedup vs baseline: 1.8469x; 1.0651x over previous
//
#include <hip/hip_runtime.h>
#include <hip/hip_fp16.h>

#define FDIM 64
#define NB_SHIFT 10                  // 1024 nodes per bucket
#define NB_PAD 256                   // padded scan width (NB <= 256)
#define CH 4096                      // edges per bin-chunk

typedef __attribute__((ext_vector_type(8))) _Float16 half8;
typedef __attribute__((ext_vector_type(4))) float floatx4;

// ---------------- CSR build ----------------

__global__ void hist_kernel(const int* __restrict__ dst, int* __restrict__ counts, int E) {
    int e = blockIdx.x * blockDim.x + threadIdx.x;
    if (e < E) atomicAdd(&counts[dst[e]], 1);
}

// exclusive scan; each block covers 1024 elements (256 thr x 4); blockSums[b] = block total
__global__ void scan_block_kernel(const int* __restrict__ in, int* __restrict__ out,
                                  int* __restrict__ blockSums, int n) {
    __shared__ int sdata[256];
    int t = threadIdx.x;
    int base = blockIdx.x * 1024 + t * 4;
    int v0 = (base + 0 < n) ? in[base + 0] : 0;
    int v1 = (base + 1 < n) ? in[base + 1] : 0;
    int v2 = (base + 2 < n) ? in[base + 2] : 0;
    int v3 = (base + 3 < n) ? in[base + 3] : 0;
    int tsum = v0 + v1 + v2 + v3;
    sdata[t] = tsum;
    __syncthreads();
    for (int off = 1; off < 256; off <<= 1) {
        int x = (t >= off) ? sdata[t - off] : 0;
        __syncthreads();
        sdata[t] += x;
        __syncthreads();
    }
    if (t == 255) blockSums[blockIdx.x] = sdata[255];
    int run = sdata[t] - tsum;  // exclusive prefix for this thread
    if (base + 0 < n) out[base + 0] = run; run += v0;
    if (base + 1 < n) out[base + 1] = run; run += v1;
    if (base + 2 < n) out[base + 2] = run; run += v2;
    if (base + 3 < n) out[base + 3] = run;
}

__global__ void add_off_kernel(int* __restrict__ row_start, const int* __restrict__ blockSums,
                               int* __restrict__ bucket_cursor, int n) {
    int i = blockIdx.x * blockDim.x + threadIdx.x;
    if (i < n) {
        int v = row_start[i] + blockSums[i >> 10];
        row_start[i] = v;
        if ((i & ((1 << NB_SHIFT) - 1)) == 0) bucket_cursor[i >> NB_SHIFT] = v;
    }
}

// Stage 1: bin edges by dst bucket with LDS staging + chunked coalesced flush.
__global__ __launch_bounds__(256) void bin_kernel(
        const int* __restrict__ src, const int* __restrict__ dst,
        const float* __restrict__ w, int* __restrict__ bucket_cursor,
        int2* __restrict__ binned_sv, unsigned short* __restrict__ binned_d,
        int E, int NB) {
    __shared__ int2 stage_sv[CH];           // 32 KB
    __shared__ int  stage_d[CH];            // 16 KB
    __shared__ int hist[NB_PAD], offs0[NB_PAD], run[NB_PAD], base[NB_PAD];

    int t = threadIdx.x;
    int c0 = blockIdx.x * CH;
    int valid = E - c0; if (valid > CH) valid = CH;

    for (int b = t; b < NB_PAD; b += 256) hist[b] = 0;
    __syncthreads();

    int  myd[16];
    int2 mysv[16];
    #pragma unroll
    for (int j = 0; j < 16; ++j) {
        int i = t + j * 256;
        if (i < valid) {
            int e = c0 + i;
            int d = dst[e];
            myd[j] = d;
            mysv[j] = make_int2(src[e], __float_as_int(-w[e]));  // norm = -w
            atomicAdd(&hist[d >> NB_SHIFT], 1);
        } else myd[j] = -1;
    }
    __syncthreads();

    // inclusive scan of hist (256-wide Hillis-Steele) -> exclusive offs
    offs0[t] = hist[t];
    __syncthreads();
    for (int off = 1; off < 256; off <<= 1) {
        int x = (t >= off) ? offs0[t - off] : 0;
        __syncthreads();
        offs0[t] += x;
        __syncthreads();
    }
    int cnt_b = hist[t];
    int excl = offs0[t] - cnt_b;
    __syncthreads();
    offs0[t] = excl;
    run[t] = excl;
    base[t] = (t < NB && cnt_b > 0) ? atomicAdd(&bucket_cursor[t], cnt_b) : 0;
    __syncthreads();

    // scatter into LDS grouped by bucket
    #pragma unroll
    for (int j = 0; j < 16; ++j) {
        if (myd[j] >= 0) {
            int b = myd[j] >> NB_SHIFT;
            int pos = atomicAdd(&run[b], 1);
            stage_sv[pos] = mysv[j];
            stage_d[pos]  = myd[j];
        }
    }
    __syncthreads();

    // flush: consecutive LDS entries of a bucket -> consecutive global slots
    for (int i = t; i < valid; i += 256) {
        int d = stage_d[i];
        int b = d >> NB_SHIFT;
        int g = base[b] + (i - offs0[b]);
        binned_sv[g] = stage_sv[i];
        binned_d[g]  = (unsigned short)(d & ((1 << NB_SHIFT) - 1));
    }
}

// Stage 2: one 1024-thread block per bucket; ranks via LDS cursors seeded from
// row_start (no global atomics). All stores to the bucket's ~130KB CSR window
// come from ONE block -> one XCD's L2 -> lines fill before eviction.
__global__ __launch_bounds__(1024) void csr_kernel(
        const int* __restrict__ row_start, const int2* __restrict__ binned_sv,
        const unsigned short* __restrict__ binned_d,
        int2* __restrict__ colval, int E, int N) {
    __shared__ int lcur[1 << NB_SHIFT];     // 4 KB
    int b = blockIdx.x;
    int t = threadIdx.x;
    int nbase = b << NB_SHIFT;
    int nextNode = (b + 1) << NB_SHIFT;

    int nloc = N - nbase; if (nloc > (1 << NB_SHIFT)) nloc = 1 << NB_SHIFT;
    if (t < nloc) lcur[t] = row_start[nbase + t];
    __syncthreads();

    int lo = row_start[nbase];
    int hi = (nextNode < N) ? row_start[nextNode] : E;
    for (int i = lo + t; i < hi; i += 1024) {
        int2 sv = binned_sv[i];
        int ld = binned_d[i];
        int p = atomicAdd(&lcur[ld], 1);
        colval[p] = sv;
    }
}

// ---------------- convert x -> fp16 (T0') ----------------

__global__ void convert_kernel(const float* __restrict__ x, __half* __restrict__ XH,
                               int total) {
    int i = (blockIdx.x * blockDim.x + threadIdx.x) * 4;
    if (i < total) {
        float4 v = *(const float4*)(x + i);
        __half2 h0 = __floats2half2_rn(v.x, v.y);
        __half2 h1 = __floats2half2_rn(v.z, v.w);
        int2 packed = make_int2(*(int*)&h0, *(int*)&h1);
        *(int2*)((char*)XH + (size_t)i * 2) = packed;
    }
}

// ---------------- prep W'T: WT[o][tk*64+fin] = 4^tk * W[tk][fin][o], fp16 ----------------

__global__ void prep_wt_kernel(const float* __restrict__ W, __half* __restrict__ WT,
                               int K) {
    int i = blockIdx.x * blockDim.x + threadIdx.x;     // over K*64*64
    if (i < K * FDIM * FDIM) {
        int tk  = i / (FDIM * FDIM);
        int rem = i - tk * FDIM * FDIM;
        int fin = rem >> 6;
        int o   = rem & 63;
        float sig = (float)(1 << (2 * tk));            // 4^tk
        WT[(size_t)o * (K * FDIM) + tk * FDIM + fin] = __float2half(sig * W[i]);
    }
}

// ---------------- Chebyshev passes (no GEMM, no LDS) ----------------
// Wave per node, lane = feature. Stored T's are fp16, scaled by sigma_k = 4^k.

#define GATHER_LOOP(SRC, ACC)                                                       \
    {                                                                               \
        int m = (cnt < 64) ? cnt : 64;                                              \
        int2 my = (lane < m) ? cv[lane] : make_int2(0, 0);                          \
        int cx = my.x;                                                              \
        float vv = __int_as_float(my.y);                                            \
        int j = 0;                                                                  \
        for (; j + 8 <= m; j += 8) {                                                \
            int c0 = __shfl(cx, j+0); float v0 = __shfl(vv, j+0);                   \
            int c1 = __shfl(cx, j+1); float v1 = __shfl(vv, j+1);                   \
            int c2 = __shfl(cx, j+2); float v2 = __shfl(vv, j+2);                   \
            int c3 = __shfl(cx, j+3); float v3 = __shfl(vv, j+3);                   \
            int c4 = __shfl(cx, j+4); float v4 = __shfl(vv, j+4);                   \
            int c5 = __shfl(cx, j+5); float v5 = __shfl(vv, j+5);                   \
            int c6 = __shfl(cx, j+6); float v6 = __shfl(vv, j+6);                   \
            int c7 = __shfl(cx, j+7); float v7 = __shfl(vv, j+7);                   \
            float t0 = __half2float(SRC[(size_t)c0 * FDIM + lane]);                 \
            float t1 = __half2float(SRC[(size_t)c1 * FDIM + lane]);                 \
            float t2 = __half2float(SRC[(size_t)c2 * FDIM + lane]);                 \
            float t3 = __half2float(SRC[(size_t)c3 * FDIM + lane]);                 \
            float t4 = __half2float(SRC[(size_t)c4 * FDIM + lane]);                 \
            float t5 = __half2float(SRC[(size_t)c5 * FDIM + lane]);                 \
            float t6 = __half2float(SRC[(size_t)c6 * FDIM + lane]);                 \
            float t7 = __half2float(SRC[(size_t)c7 * FDIM + lane]);                 \
            ACC += v0*t0 + v1*t1 + v2*t2 + v3*t3 + v4*t4 + v5*t5 + v6*t6 + v7*t7;   \
        }                                                                           \
        for (; j < m; ++j) {                                                        \
            int c = __shfl(cx, j); float v = __shfl(vv, j);                         \
            ACC += v * __half2float(SRC[(size_t)c * FDIM + lane]);                  \
        }                                                                           \
        for (int e2 = 64; e2 < cnt; ++e2) {  /* astronomically rare */              \
            int2 a = cv[e2];                                                        \
            ACC += __int_as_float(a.y) * __half2float(SRC[(size_t)a.x * FDIM + lane]); \
        }                                                                           \
    }

__global__ __launch_bounds__(256, 8) void pass1_kernel(
        const __half* __restrict__ XH, const int* __restrict__ row_start,
        const int* __restrict__ counts, const int2* __restrict__ colval,
        __half* __restrict__ T1H, int N) {
    int wid = threadIdx.x >> 6;
    int lane = threadIdx.x & 63;
    int node = blockIdx.x * 4 + wid;
    if (node >= N) return;

    float acc = -__half2float(XH[(size_t)node * FDIM + lane]);   // self loop (norm -1)
    int s = row_start[node];
    int cnt = counts[node];
    const int2* cv = colval + s;
    GATHER_LOOP(XH, acc)
    T1H[(size_t)node * FDIM + lane] = __float2half(acc * 0.25f);  // sigma1 = 4
}

// T'_next = 0.5*prop'(T'_cur) - T'_prev/16
__global__ __launch_bounds__(256, 8) void passk_kernel(
        const __half* __restrict__ TcH, const __half* __restrict__ TpH,
        __half* __restrict__ TnH, const int* __restrict__ row_start,
        const int* __restrict__ counts, const int2* __restrict__ colval, int N) {
    int wid = threadIdx.x >> 6;
    int lane = threadIdx.x & 63;
    int node = blockIdx.x * 4 + wid;
    if (node >= N) return;

    size_t self = (size_t)node * FDIM + lane;
    int s = row_start[node];
    int cnt = counts[node];
    const int2* cv = colval + s;
    float acc = -__half2float(TcH[self]);                        // self loop
    GATHER_LOOP(TcH, acc)
    float tns = 0.5f * acc - 0.0625f * __half2float(TpH[self]);
    TnH[self] = __float2half(tns);
}

// ---------------- final: out = [T'0|...|T'5] @ W'T^T + bias via MFMA ----------------
// A = N x (K*64) fp16 (the stored T' planes), B = W'T (sigma folded), C fp32.
// Wave computes a 16-node x 64-out tile with 4x mfma_f32_16x16x32_f16 per K-chunk.
// Fragment layout (m89-verified family): A lane l -> (row=l&15, k=(l>>4)*8+j);
// B lane l -> (k=(l>>4)*8+j, col=l&15); D lane l reg r -> (row=(l>>4)*4+r, col=l&15).

__global__ __launch_bounds__(256) void final_mfma_kernel(
        const __half* __restrict__ Tall, const __half* __restrict__ WT,
        const float* __restrict__ bias, float* __restrict__ out,
        int N, int K) {
    int wid = threadIdx.x >> 6;
    int lane = threadIdx.x & 63;
    int tile = blockIdx.x * 4 + wid;       // 16 nodes per wave-tile
    int nodeBase = tile << 4;
    if (nodeBase >= N) return;
    size_t NT = (size_t)N * FDIM;
    int Kflat = K * FDIM;                  // 384

    int m = lane & 15;
    int kgrp = lane >> 4;                  // 0..3
    int nodeA = nodeBase + m;              // A-fragment row
    bool aok = nodeA < N;

    floatx4 acc[4];
    #pragma unroll
    for (int f = 0; f < 4; ++f) {
        float bv = bias[f * 16 + m];
        acc[f] = (floatx4){bv, bv, bv, bv};
    }

    for (int kc = 0; kc < Kflat / 32; ++kc) {
        int tk = kc >> 1;
        int feat = ((kc & 1) << 5) + (kgrp << 3);    // 0..56, 8-aligned
        half8 a = aok ? *(const half8*)(Tall + (size_t)tk * NT + (size_t)nodeA * FDIM + feat)
                      : (half8)(_Float16)0;
        int kOff = (kc << 5) + (kgrp << 3);
        #pragma unroll
        for (int f = 0; f < 4; ++f) {
            half8 b = *(const half8*)(WT + (size_t)(f * 16 + m) * Kflat + kOff);
            acc[f] = __builtin_amdgcn_mfma_f32_16x16x32_f16(a, b, acc[f], 0, 0, 0);
        }
    }

    #pragma unroll
    for (int f = 0; f < 4; ++f) {
        #pragma unroll
        for (int r = 0; r < 4; ++r) {
            int nrow = nodeBase + (kgrp << 2) + r;
            if (nrow < N) out[(size_t)nrow * FDIM + f * 16 + m] = acc[f][r];
        }
    }
}

// ---------------- host ----------------

extern "C" void kernel_launch(void* const* d_in, const int* in_sizes, int n_in,
                              void* d_out, int out_size, void* d_ws, size_t ws_size,
                              hipStream_t stream) {
    const float* x      = (const float*)d_in[0];
    const int*   idx    = (const int*)d_in[1];
    const float* w      = (const float*)d_in[2];
    const float* weight = (const float*)d_in[3];
    const float* bias   = (const float*)d_in[4];
    float* out = (float*)d_out;

    const int N = in_sizes[0] / FDIM;
    const int E = in_sizes[2];
    const int K = in_sizes[3] / (FDIM * FDIM);
    const int NB = (N + (1 << NB_SHIFT) - 1) >> NB_SHIFT;

    const int* src = idx;
    const int* dst = idx + E;

    int* counts        = (int*)d_ws;                 // N
    int* row_start     = counts + N;                 // N
    int* blockSums     = row_start + N;              // 512
    int* bucket_cursor = blockSums + 512;            // 256
    int2* colval       = (int2*)(bucket_cursor + 256);      // E, 8B-aligned
    __half* Tall       = (__half*)(colval + E);             // K * N*FDIM fp16
    __half* WT         = Tall + (size_t)K * N * FDIM;       // K*64*64 fp16
    // binned arrays alias T0/T1 (dead before convert/pass1 write them)
    int2* binned_sv    = (int2*)Tall;                       // E * 8B
    unsigned short* binned_d = (unsigned short*)(Tall + (size_t)N * FDIM);  // E * 2B

    hipMemsetAsync(counts, 0, (size_t)N * sizeof(int), stream);

    int eb = (E + 255) / 256;
    hist_kernel<<<eb, 256, 0, stream>>>(dst, counts, E);

    int nb = (N + 1023) / 1024;
    scan_block_kernel<<<nb, 256, 0, stream>>>(counts, row_start, blockSums, N);
    scan_block_kernel<<<1, 256, 0, stream>>>(blockSums, blockSums, blockSums + 500, nb);
    add_off_kernel<<<(N + 255) / 256, 256, 0, stream>>>(row_start, blockSums,
                                                        bucket_cursor, N);

    int bb = (E + CH - 1) / CH;
    bin_kernel<<<bb, 256, 0, stream>>>(src, dst, w, bucket_cursor,
                                       binned_sv, binned_d, E, NB);
    csr_kernel<<<NB, 1024, 0, stream>>>(row_start, binned_sv, binned_d,
                                        colval, E, N);

    // T0' = x (fp16); W'T prep (sigma folded into W, fp16)
    convert_kernel<<<(N * FDIM + 1023) / 1024, 256, 0, stream>>>(x, Tall, N * FDIM);
    prep_wt_kernel<<<(K * FDIM * FDIM + 255) / 256, 256, 0, stream>>>(weight, WT, K);

    size_t NT = (size_t)N * FDIM;
    __half* T[8];
    for (int k = 0; k < K && k < 8; ++k) T[k] = Tall + (size_t)k * NT;

    int pb = (N + 3) / 4;
    pass1_kernel<<<pb, 256, 0, stream>>>(T[0], row_start, counts, colval, T[1], N);
    for (int k = 2; k < K; ++k) {
        passk_kernel<<<pb, 256, 0, stream>>>(T[k-1], T[k-2], T[k], row_start, counts,
                                             colval, N);
    }

    int tiles = (N + 15) >> 4;
    final_mfma_kernel<<<(tiles + 3) / 4, 256, 0, stream>>>(Tall, WT, bias, out, N, K);
}

// Round 8
// 820.808 us; speedup vs baseline: 1.8938x; 1.0254x over previous
//
#include <hip/hip_runtime.h>
#include <hip/hip_fp16.h>

#define FDIM 64
#define NB_SHIFT 10                  // 1024 nodes per bucket
#define NB_PAD 256                   // padded scan width (NB <= 256)
#define CH 4096                      // edges per bin-chunk

typedef __attribute__((ext_vector_type(8))) _Float16 half8;
typedef __attribute__((ext_vector_type(4))) float floatx4;

// ---------------- bucket-level CSR build (no per-node global atomics) ----------------

// 196-bucket histogram: LDS-local, one global atomicAdd per bucket per block.
__global__ __launch_bounds__(256) void bucket_hist_kernel(
        const int* __restrict__ dst, int* __restrict__ bucket_cnt, int E) {
    __shared__ int h[NB_PAD];
    for (int i = threadIdx.x; i < NB_PAD; i += 256) h[i] = 0;
    __syncthreads();
    int stride = gridDim.x * 256;
    for (int e = blockIdx.x * 256 + threadIdx.x; e < E; e += stride)
        atomicAdd(&h[dst[e] >> NB_SHIFT], 1);
    __syncthreads();
    for (int i = threadIdx.x; i < NB_PAD; i += 256)
        if (h[i]) atomicAdd(&bucket_cnt[i], h[i]);
}

// single block: exclusive scan of bucket counts -> bucket_base[0..NB] and cursors.
__global__ __launch_bounds__(256) void bucket_scan_kernel(
        const int* __restrict__ bucket_cnt, int* __restrict__ bucket_base,
        int* __restrict__ bucket_cursor) {
    __shared__ int s[NB_PAD];
    int t = threadIdx.x;
    int v = bucket_cnt[t];
    s[t] = v;
    __syncthreads();
    for (int off = 1; off < 256; off <<= 1) {
        int x = (t >= off) ? s[t - off] : 0;
        __syncthreads();
        s[t] += x;
        __syncthreads();
    }
    int excl = s[t] - v;
    bucket_base[t] = excl;                  // for t >= NB this equals E (cnt=0)
    if (t == 255) bucket_base[256] = s[255];
    bucket_cursor[t] = excl;
}

// Stage 1: bin edges by dst bucket with LDS staging + chunked coalesced flush.
__global__ __launch_bounds__(256) void bin_kernel(
        const int* __restrict__ src, const int* __restrict__ dst,
        const float* __restrict__ w, int* __restrict__ bucket_cursor,
        int2* __restrict__ binned_sv, unsigned short* __restrict__ binned_d,
        int E, int NB) {
    __shared__ int2 stage_sv[CH];           // 32 KB
    __shared__ int  stage_d[CH];            // 16 KB
    __shared__ int hist[NB_PAD], offs0[NB_PAD], run[NB_PAD], base[NB_PAD];

    int t = threadIdx.x;
    int c0 = blockIdx.x * CH;
    int valid = E - c0; if (valid > CH) valid = CH;

    for (int b = t; b < NB_PAD; b += 256) hist[b] = 0;
    __syncthreads();

    int  myd[16];
    int2 mysv[16];
    #pragma unroll
    for (int j = 0; j < 16; ++j) {
        int i = t + j * 256;
        if (i < valid) {
            int e = c0 + i;
            int d = dst[e];
            myd[j] = d;
            mysv[j] = make_int2(src[e], __float_as_int(-w[e]));  // norm = -w
            atomicAdd(&hist[d >> NB_SHIFT], 1);
        } else myd[j] = -1;
    }
    __syncthreads();

    // inclusive scan of hist (256-wide Hillis-Steele) -> exclusive offs
    offs0[t] = hist[t];
    __syncthreads();
    for (int off = 1; off < 256; off <<= 1) {
        int x = (t >= off) ? offs0[t - off] : 0;
        __syncthreads();
        offs0[t] += x;
        __syncthreads();
    }
    int cnt_b = hist[t];
    int excl = offs0[t] - cnt_b;
    __syncthreads();
    offs0[t] = excl;
    run[t] = excl;
    base[t] = (t < NB && cnt_b > 0) ? atomicAdd(&bucket_cursor[t], cnt_b) : 0;
    __syncthreads();

    // scatter into LDS grouped by bucket
    #pragma unroll
    for (int j = 0; j < 16; ++j) {
        if (myd[j] >= 0) {
            int b = myd[j] >> NB_SHIFT;
            int pos = atomicAdd(&run[b], 1);
            stage_sv[pos] = mysv[j];
            stage_d[pos]  = myd[j];
        }
    }
    __syncthreads();

    // flush: consecutive LDS entries of a bucket -> consecutive global slots
    for (int i = t; i < valid; i += 256) {
        int d = stage_d[i];
        int b = d >> NB_SHIFT;
        int g = base[b] + (i - offs0[b]);
        binned_sv[g] = stage_sv[i];
        binned_d[g]  = (unsigned short)(d & ((1 << NB_SHIFT) - 1));
    }
}

// Stage 2: one 1024-thread block per bucket. Local histogram + local scan in LDS
// produce row_start/counts for the bucket's nodes (no global atomics), then edges
// are placed; the ~130KB CSR window stays in ONE XCD's L2.
__global__ __launch_bounds__(1024) void csr_kernel(
        const int* __restrict__ bucket_base, const int2* __restrict__ binned_sv,
        const unsigned short* __restrict__ binned_d,
        int* __restrict__ row_start, int* __restrict__ counts,
        int2* __restrict__ colval, int N) {
    __shared__ int lhist[1 << NB_SHIFT];    // 4 KB
    __shared__ int lscan[1 << NB_SHIFT];    // 4 KB
    int b = blockIdx.x;
    int t = threadIdx.x;
    int nbase = b << NB_SHIFT;
    int lo = bucket_base[b];
    int hi = bucket_base[b + 1];

    lhist[t] = 0;
    __syncthreads();
    for (int i = lo + t; i < hi; i += 1024)
        atomicAdd(&lhist[binned_d[i]], 1);
    __syncthreads();

    int v = lhist[t];
    lscan[t] = v;
    __syncthreads();
    for (int off = 1; off < 1024; off <<= 1) {
        int x = (t >= off) ? lscan[t - off] : 0;
        __syncthreads();
        lscan[t] += x;
        __syncthreads();
    }
    int rs = lo + lscan[t] - v;             // node's CSR start
    int node = nbase + t;
    if (node < N) {
        row_start[node] = rs;
        counts[node] = v;
    }
    __syncthreads();
    lscan[t] = rs;                          // reuse as local cursor
    __syncthreads();

    for (int i = lo + t; i < hi; i += 1024) {
        int2 sv = binned_sv[i];
        int p = atomicAdd(&lscan[binned_d[i]], 1);
        colval[p] = sv;
    }
}

// ---------------- convert x -> fp16 (T0') ----------------

__global__ void convert_kernel(const float* __restrict__ x, __half* __restrict__ XH,
                               int total) {
    int i = (blockIdx.x * blockDim.x + threadIdx.x) * 4;
    if (i < total) {
        float4 v = *(const float4*)(x + i);
        __half2 h0 = __floats2half2_rn(v.x, v.y);
        __half2 h1 = __floats2half2_rn(v.z, v.w);
        int2 packed = make_int2(*(int*)&h0, *(int*)&h1);
        *(int2*)((char*)XH + (size_t)i * 2) = packed;
    }
}

// ---------------- prep W'T: WT[o][tk*64+fin] = 4^tk * W[tk][fin][o], fp16 ----------------

__global__ void prep_wt_kernel(const float* __restrict__ W, __half* __restrict__ WT,
                               int K) {
    int i = blockIdx.x * blockDim.x + threadIdx.x;     // over K*64*64
    if (i < K * FDIM * FDIM) {
        int tk  = i / (FDIM * FDIM);
        int rem = i - tk * FDIM * FDIM;
        int fin = rem >> 6;
        int o   = rem & 63;
        float sig = (float)(1 << (2 * tk));            // 4^tk
        WT[(size_t)o * (K * FDIM) + tk * FDIM + fin] = __float2half(sig * W[i]);
    }
}

// ---------------- Chebyshev passes (no GEMM, no LDS) ----------------
// Wave per node, lane = feature. Stored T's are fp16, scaled by sigma_k = 4^k.

#define GATHER_LOOP(SRC, ACC)                                                       \
    {                                                                               \
        int m = (cnt < 64) ? cnt : 64;                                              \
        int2 my = (lane < m) ? cv[lane] : make_int2(0, 0);                          \
        int cx = my.x;                                                              \
        float vv = __int_as_float(my.y);                                            \
        int j = 0;                                                                  \
        for (; j + 8 <= m; j += 8) {                                                \
            int c0 = __shfl(cx, j+0); float v0 = __shfl(vv, j+0);                   \
            int c1 = __shfl(cx, j+1); float v1 = __shfl(vv, j+1);                   \
            int c2 = __shfl(cx, j+2); float v2 = __shfl(vv, j+2);                   \
            int c3 = __shfl(cx, j+3); float v3 = __shfl(vv, j+3);                   \
            int c4 = __shfl(cx, j+4); float v4 = __shfl(vv, j+4);                   \
            int c5 = __shfl(cx, j+5); float v5 = __shfl(vv, j+5);                   \
            int c6 = __shfl(cx, j+6); float v6 = __shfl(vv, j+6);                   \
            int c7 = __shfl(cx, j+7); float v7 = __shfl(vv, j+7);                   \
            float t0 = __half2float(SRC[(size_t)c0 * FDIM + lane]);                 \
            float t1 = __half2float(SRC[(size_t)c1 * FDIM + lane]);                 \
            float t2 = __half2float(SRC[(size_t)c2 * FDIM + lane]);                 \
            float t3 = __half2float(SRC[(size_t)c3 * FDIM + lane]);                 \
            float t4 = __half2float(SRC[(size_t)c4 * FDIM + lane]);                 \
            float t5 = __half2float(SRC[(size_t)c5 * FDIM + lane]);                 \
            float t6 = __half2float(SRC[(size_t)c6 * FDIM + lane]);                 \
            float t7 = __half2float(SRC[(size_t)c7 * FDIM + lane]);                 \
            ACC += v0*t0 + v1*t1 + v2*t2 + v3*t3 + v4*t4 + v5*t5 + v6*t6 + v7*t7;   \
        }                                                                           \
        for (; j < m; ++j) {                                                        \
            int c = __shfl(cx, j); float v = __shfl(vv, j);                         \
            ACC += v * __half2float(SRC[(size_t)c * FDIM + lane]);                  \
        }                                                                           \
        for (int e2 = 64; e2 < cnt; ++e2) {  /* astronomically rare */              \
            int2 a = cv[e2];                                                        \
            ACC += __int_as_float(a.y) * __half2float(SRC[(size_t)a.x * FDIM + lane]); \
        }                                                                           \
    }

__global__ __launch_bounds__(256, 8) void pass1_kernel(
        const __half* __restrict__ XH, const int* __restrict__ row_start,
        const int* __restrict__ counts, const int2* __restrict__ colval,
        __half* __restrict__ T1H, int N) {
    int wid = threadIdx.x >> 6;
    int lane = threadIdx.x & 63;
    int node = blockIdx.x * 4 + wid;
    if (node >= N) return;

    float acc = -__half2float(XH[(size_t)node * FDIM + lane]);   // self loop (norm -1)
    int s = row_start[node];
    int cnt = counts[node];
    const int2* cv = colval + s;
    GATHER_LOOP(XH, acc)
    T1H[(size_t)node * FDIM + lane] = __float2half(acc * 0.25f);  // sigma1 = 4
}

// T'_next = 0.5*prop'(T'_cur) - T'_prev/16
__global__ __launch_bounds__(256, 8) void passk_kernel(
        const __half* __restrict__ TcH, const __half* __restrict__ TpH,
        __half* __restrict__ TnH, const int* __restrict__ row_start,
        const int* __restrict__ counts, const int2* __restrict__ colval, int N) {
    int wid = threadIdx.x >> 6;
    int lane = threadIdx.x & 63;
    int node = blockIdx.x * 4 + wid;
    if (node >= N) return;

    size_t self = (size_t)node * FDIM + lane;
    int s = row_start[node];
    int cnt = counts[node];
    const int2* cv = colval + s;
    float acc = -__half2float(TcH[self]);                        // self loop
    GATHER_LOOP(TcH, acc)
    float tns = 0.5f * acc - 0.0625f * __half2float(TpH[self]);
    TnH[self] = __float2half(tns);
}

// ---------------- final: out = [T'0|...|T'5] @ W'T^T + bias via MFMA ----------------

__global__ __launch_bounds__(256) void final_mfma_kernel(
        const __half* __restrict__ Tall, const __half* __restrict__ WT,
        const float* __restrict__ bias, float* __restrict__ out,
        int N, int K) {
    int wid = threadIdx.x >> 6;
    int lane = threadIdx.x & 63;
    int tile = blockIdx.x * 4 + wid;       // 16 nodes per wave-tile
    int nodeBase = tile << 4;
    if (nodeBase >= N) return;
    size_t NT = (size_t)N * FDIM;
    int Kflat = K * FDIM;                  // 384

    int m = lane & 15;
    int kgrp = lane >> 4;                  // 0..3
    int nodeA = nodeBase + m;              // A-fragment row
    bool aok = nodeA < N;

    floatx4 acc[4];
    #pragma unroll
    for (int f = 0; f < 4; ++f) {
        float bv = bias[f * 16 + m];
        acc[f] = (floatx4){bv, bv, bv, bv};
    }

    for (int kc = 0; kc < Kflat / 32; ++kc) {
        int tk = kc >> 1;
        int feat = ((kc & 1) << 5) + (kgrp << 3);    // 0..56, 8-aligned
        half8 a = aok ? *(const half8*)(Tall + (size_t)tk * NT + (size_t)nodeA * FDIM + feat)
                      : (half8)(_Float16)0;
        int kOff = (kc << 5) + (kgrp << 3);
        #pragma unroll
        for (int f = 0; f < 4; ++f) {
            half8 b = *(const half8*)(WT + (size_t)(f * 16 + m) * Kflat + kOff);
            acc[f] = __builtin_amdgcn_mfma_f32_16x16x32_f16(a, b, acc[f], 0, 0, 0);
        }
    }

    #pragma unroll
    for (int f = 0; f < 4; ++f) {
        #pragma unroll
        for (int r = 0; r < 4; ++r) {
            int nrow = nodeBase + (kgrp << 2) + r;
            if (nrow < N) out[(size_t)nrow * FDIM + f * 16 + m] = acc[f][r];
        }
    }
}

// ---------------- host ----------------

extern "C" void kernel_launch(void* const* d_in, const int* in_sizes, int n_in,
                              void* d_out, int out_size, void* d_ws, size_t ws_size,
                              hipStream_t stream) {
    const float* x      = (const float*)d_in[0];
    const int*   idx    = (const int*)d_in[1];
    const float* w      = (const float*)d_in[2];
    const float* weight = (const float*)d_in[3];
    const float* bias   = (const float*)d_in[4];
    float* out = (float*)d_out;

    const int N = in_sizes[0] / FDIM;
    const int E = in_sizes[2];
    const int K = in_sizes[3] / (FDIM * FDIM);
    const int NB = (N + (1 << NB_SHIFT) - 1) >> NB_SHIFT;

    const int* src = idx;
    const int* dst = idx + E;

    int* counts        = (int*)d_ws;                 // N
    int* row_start     = counts + N;                 // N
    int* bucket_cnt    = row_start + N;              // 256
    int* bucket_base   = bucket_cnt + 256;           // 260
    int* bucket_cursor = bucket_base + 260;          // 256
    int2* colval       = (int2*)(bucket_cursor + 256 + 4);  // E, 8B-aligned
    __half* Tall       = (__half*)(colval + E);             // K * N*FDIM fp16
    __half* WT         = Tall + (size_t)K * N * FDIM;       // K*64*64 fp16
    // binned arrays alias T0/T1 (dead before convert/pass1 write them)
    int2* binned_sv    = (int2*)Tall;                       // E * 8B
    unsigned short* binned_d = (unsigned short*)(Tall + (size_t)N * FDIM);  // E * 2B

    hipMemsetAsync(bucket_cnt, 0, 256 * sizeof(int), stream);

    bucket_hist_kernel<<<512, 256, 0, stream>>>(dst, bucket_cnt, E);
    bucket_scan_kernel<<<1, 256, 0, stream>>>(bucket_cnt, bucket_base, bucket_cursor);

    int bb = (E + CH - 1) / CH;
    bin_kernel<<<bb, 256, 0, stream>>>(src, dst, w, bucket_cursor,
                                       binned_sv, binned_d, E, NB);
    csr_kernel<<<NB, 1024, 0, stream>>>(bucket_base, binned_sv, binned_d,
                                        row_start, counts, colval, N);

    // T0' = x (fp16); W'T prep (sigma folded into W, fp16)
    convert_kernel<<<(N * FDIM + 1023) / 1024, 256, 0, stream>>>(x, Tall, N * FDIM);
    prep_wt_kernel<<<(K * FDIM * FDIM + 255) / 256, 256, 0, stream>>>(weight, WT, K);

    size_t NT = (size_t)N * FDIM;
    __half* T[8];
    for (int k = 0; k < K && k < 8; ++k) T[k] = Tall + (size_t)k * NT;

    int pb = (N + 3) / 4;
    pass1_kernel<<<pb, 256, 0, stream>>>(T[0], row_start, counts, colval, T[1], N);
    for (int k = 2; k < K; ++k) {
        passk_kernel<<<pb, 256, 0, stream>>>(T[k-1], T[k-2], T[k], row_start, counts,
                                             colval, N);
    }

    int tiles = (N + 15) >> 4;
    final_mfma_kernel<<<(tiles + 3) / 4, 256, 0, stream>>>(Tall, WT, bias, out, N, K);
}